// Round 3
// baseline (661.335 us; speedup 1.0000x reference)
//
#include <hip/hip_runtime.h>
#include <math.h>

#define Bn   128
#define Cn   2048
#define Hn   24
#define Wn   12
#define HID  768
#define NIN  1536
#define NST  16
#define DTR  48
#define Ln   9
#define Mn   (Bn*Ln)   // 1152

typedef __bf16 bf16x8 __attribute__((ext_vector_type(8)));
typedef float  f32x4  __attribute__((ext_vector_type(4)));

__device__ __forceinline__ unsigned short f2bf(float f) {
  unsigned u = __float_as_uint(f);
  u += 0x7fffu + ((u >> 16) & 1u);           // round-to-nearest-even
  return (unsigned short)(u >> 16);
}
__device__ __forceinline__ float bf2f(unsigned short h) {
  return __uint_as_float(((unsigned)h) << 16);
}
__device__ __forceinline__ void split_bf(float f, unsigned short& hi, unsigned short& lo) {
  hi = f2bf(f);
  lo = f2bf(f - bf2f(hi));
}

// ---------------- pooling: x (B,C,24,12) -> tok (B*9, C) as bf16 hi/lo ----------------
__global__ __launch_bounds__(256) void pool_kernel(const float* __restrict__ x,
    unsigned short* __restrict__ thi, unsigned short* __restrict__ tlo) {
  int idx = blockIdx.x * 256 + threadIdx.x;           // over B*C
  if (idx >= Bn * Cn) return;
  int b = idx / Cn, c = idx - b * Cn;
  const float4* p = reinterpret_cast<const float4*>(x + (size_t)idx * (Hn * Wn));
  float s[9] = {0,0,0,0,0,0,0,0,0};
  #pragma unroll
  for (int h = 0; h < 24; ++h) {
    int i = h >> 3;
    #pragma unroll
    for (int j = 0; j < 3; ++j) {
      float4 v = p[h * 3 + j];
      s[i * 3 + j] += (v.x + v.y) + (v.z + v.w);
    }
  }
  #pragma unroll
  for (int pp = 0; pp < 9; ++pp) {
    float v = s[pp] * (1.0f / 32.0f);
    unsigned short hi, lo;
    split_bf(v, hi, lo);
    size_t o = ((size_t)(b * Ln + pp)) * Cn + c;
    thi[o] = hi; tlo[o] = lo;
  }
}

// ---------------- fp32 W[K][N] -> transposed bf16-split WT[N][K] ----------------
__global__ __launch_bounds__(256) void tconv_kernel(const float* __restrict__ W,
    int K, int N, unsigned short* __restrict__ Thi, unsigned short* __restrict__ Tlo) {
  __shared__ float tile[32][33];
  int nb = blockIdx.x, kb = blockIdx.y;
  int t = threadIdx.x;
  int kl = t >> 3, n4 = (t & 7) * 4;
  float4 v = *reinterpret_cast<const float4*>(W + (size_t)(kb * 32 + kl) * N + nb * 32 + n4);
  tile[kl][n4] = v.x; tile[kl][n4 + 1] = v.y; tile[kl][n4 + 2] = v.z; tile[kl][n4 + 3] = v.w;
  __syncthreads();
  int nl = t >> 3, k4 = (t & 7) * 4;
  unsigned short hi[4], lo[4];
  #pragma unroll
  for (int i = 0; i < 4; ++i) split_bf(tile[k4 + i][nl], hi[i], lo[i]);
  size_t o = (size_t)(nb * 32 + nl) * K + kb * 32 + k4;
  uint2 ph, pl;
  ph.x = (unsigned)hi[0] | ((unsigned)hi[1] << 16);
  ph.y = (unsigned)hi[2] | ((unsigned)hi[3] << 16);
  pl.x = (unsigned)lo[0] | ((unsigned)lo[1] << 16);
  pl.y = (unsigned)lo[2] | ((unsigned)lo[3] << 16);
  *reinterpret_cast<uint2*>(Thi + o) = ph;
  *reinterpret_cast<uint2*>(Tlo + o) = pl;
}

// ------------- split-bf16 MFMA GEMM: C(M,N) = A(M,K) * B^T(N,K) -------------
// 64x64 tile, BK=64, 4 waves of 32x32, register prefetch of next K-tile.
template<int BIAS>
__global__ __launch_bounds__(256) void mgemm_kernel(
    const unsigned short* __restrict__ Ahi, const unsigned short* __restrict__ Alo,
    const unsigned short* __restrict__ Bhi, const unsigned short* __restrict__ Blo,
    const float* __restrict__ bias, float* __restrict__ C, int M, int N, int K) {
  __shared__ unsigned short As[2][64][64];
  __shared__ unsigned short Bs[2][64][64];
  int t = threadIdx.x;
  int bm = blockIdx.y * 64, bn = blockIdx.x * 64;
  int wave = t >> 6, lane = t & 63;
  int wr = (wave >> 1) * 32, wc = (wave & 1) * 32;
  int lr = lane & 15, lk = lane >> 4;

  f32x4 acc[2][2];
  #pragma unroll
  for (int m = 0; m < 2; ++m)
    #pragma unroll
    for (int n = 0; n < 2; ++n) acc[m][n] = {0.f, 0.f, 0.f, 0.f};

  int sr = t >> 3;                 // staging row 0..31 (and sr+32)
  int sc = t & 7;                  // 16B chunk col 0..7
  int sd = (sc ^ (sr & 7)) * 8;    // swizzled dest (same for sr and sr+32)

  float4 pre[8];
  size_t gA0 = (size_t)(bm + sr) * K + sc * 8;
  size_t gB0 = (size_t)(bn + sr) * K + sc * 8;
  size_t strA = (size_t)32 * K;

  // prologue load k0=0
  pre[0] = *reinterpret_cast<const float4*>(Ahi + gA0);
  pre[1] = *reinterpret_cast<const float4*>(Ahi + gA0 + strA);
  pre[2] = *reinterpret_cast<const float4*>(Alo + gA0);
  pre[3] = *reinterpret_cast<const float4*>(Alo + gA0 + strA);
  pre[4] = *reinterpret_cast<const float4*>(Bhi + gB0);
  pre[5] = *reinterpret_cast<const float4*>(Bhi + gB0 + strA);
  pre[6] = *reinterpret_cast<const float4*>(Blo + gB0);
  pre[7] = *reinterpret_cast<const float4*>(Blo + gB0 + strA);

  for (int k0 = 0;; k0 += 64) {
    __syncthreads();   // previous iteration's LDS reads done
    *reinterpret_cast<float4*>(&As[0][sr     ][sd]) = pre[0];
    *reinterpret_cast<float4*>(&As[0][sr + 32][sd]) = pre[1];
    *reinterpret_cast<float4*>(&As[1][sr     ][sd]) = pre[2];
    *reinterpret_cast<float4*>(&As[1][sr + 32][sd]) = pre[3];
    *reinterpret_cast<float4*>(&Bs[0][sr     ][sd]) = pre[4];
    *reinterpret_cast<float4*>(&Bs[0][sr + 32][sd]) = pre[5];
    *reinterpret_cast<float4*>(&Bs[1][sr     ][sd]) = pre[6];
    *reinterpret_cast<float4*>(&Bs[1][sr + 32][sd]) = pre[7];
    __syncthreads();

    bool last = (k0 + 64 >= K);
    if (!last) {
      size_t a0 = gA0 + k0 + 64, b0 = gB0 + k0 + 64;
      pre[0] = *reinterpret_cast<const float4*>(Ahi + a0);
      pre[1] = *reinterpret_cast<const float4*>(Ahi + a0 + strA);
      pre[2] = *reinterpret_cast<const float4*>(Alo + a0);
      pre[3] = *reinterpret_cast<const float4*>(Alo + a0 + strA);
      pre[4] = *reinterpret_cast<const float4*>(Bhi + b0);
      pre[5] = *reinterpret_cast<const float4*>(Bhi + b0 + strA);
      pre[6] = *reinterpret_cast<const float4*>(Blo + b0);
      pre[7] = *reinterpret_cast<const float4*>(Blo + b0 + strA);
    }

    bf16x8 ah[2][2], al[2][2], bh[2][2], bl[2][2];
    #pragma unroll
    for (int m = 0; m < 2; ++m) {
      int arow = wr + m * 16 + lr;
      #pragma unroll
      for (int ks = 0; ks < 2; ++ks) {
        int cc = (((ks << 2) + lk) ^ (arow & 7)) * 8;
        ah[m][ks] = *reinterpret_cast<const bf16x8*>(&As[0][arow][cc]);
        al[m][ks] = *reinterpret_cast<const bf16x8*>(&As[1][arow][cc]);
      }
    }
    #pragma unroll
    for (int n = 0; n < 2; ++n) {
      int brow = wc + n * 16 + lr;
      #pragma unroll
      for (int ks = 0; ks < 2; ++ks) {
        int cc = (((ks << 2) + lk) ^ (brow & 7)) * 8;
        bh[n][ks] = *reinterpret_cast<const bf16x8*>(&Bs[0][brow][cc]);
        bl[n][ks] = *reinterpret_cast<const bf16x8*>(&Bs[1][brow][cc]);
      }
    }
    #pragma unroll
    for (int m = 0; m < 2; ++m)
      #pragma unroll
      for (int n = 0; n < 2; ++n)
        #pragma unroll
        for (int ks = 0; ks < 2; ++ks) {
          acc[m][n] = __builtin_amdgcn_mfma_f32_16x16x32_bf16(ah[m][ks], bh[n][ks], acc[m][n], 0, 0, 0);
          acc[m][n] = __builtin_amdgcn_mfma_f32_16x16x32_bf16(ah[m][ks], bl[n][ks], acc[m][n], 0, 0, 0);
          acc[m][n] = __builtin_amdgcn_mfma_f32_16x16x32_bf16(al[m][ks], bh[n][ks], acc[m][n], 0, 0, 0);
        }
    if (last) break;
  }

  #pragma unroll
  for (int m = 0; m < 2; ++m)
    #pragma unroll
    for (int n = 0; n < 2; ++n) {
      int col = bn + wc + n * 16 + lr;
      float bv = BIAS ? bias[col] : 0.0f;
      #pragma unroll
      for (int r = 0; r < 4; ++r) {
        int row = bm + wr + m * 16 + lk * 4 + r;
        C[(size_t)row * N + col] = acc[m][n][r] + bv;
      }
    }
}

// ---------------- generic fp32 tiled GEMM (dtproj only) ----------------
template<int ACT>
__global__ __launch_bounds__(256) void gemm_kernel(const float* __restrict__ A, int lda,
    const float* __restrict__ Bm, const float* __restrict__ bias, float* __restrict__ Cm,
    int M, int N, int K) {
  __shared__ float As[16][68];
  __shared__ float Bs[16][68];
  int t  = threadIdx.x;
  int bm = blockIdx.y * 64, bn = blockIdx.x * 64;
  int tx = t & 15, ty = t >> 4;
  float acc[4][4] = {};
  int ar = t >> 2, ak = (t & 3) * 4;
  int br = t >> 4, bc = (t & 15) * 4;
  for (int k0 = 0; k0 < K; k0 += 16) {
    float4 av = make_float4(0.f, 0.f, 0.f, 0.f);
    if (bm + ar < M)
      av = *reinterpret_cast<const float4*>(A + (size_t)(bm + ar) * lda + k0 + ak);
    As[ak + 0][ar] = av.x; As[ak + 1][ar] = av.y;
    As[ak + 2][ar] = av.z; As[ak + 3][ar] = av.w;
    float4 bv = make_float4(0.f, 0.f, 0.f, 0.f);
    if (bn + bc < N)
      bv = *reinterpret_cast<const float4*>(Bm + (size_t)(k0 + br) * N + bn + bc);
    *reinterpret_cast<float4*>(&Bs[br][bc]) = bv;
    __syncthreads();
    #pragma unroll
    for (int kk = 0; kk < 16; ++kk) {
      float a0[4], b0[4];
      #pragma unroll
      for (int i = 0; i < 4; ++i) a0[i] = As[kk][ty * 4 + i];
      #pragma unroll
      for (int j = 0; j < 4; ++j) b0[j] = Bs[kk][tx * 4 + j];
      #pragma unroll
      for (int i = 0; i < 4; ++i)
        #pragma unroll
        for (int j = 0; j < 4; ++j)
          acc[i][j] = fmaf(a0[i], b0[j], acc[i][j]);
    }
    __syncthreads();
  }
  #pragma unroll
  for (int i = 0; i < 4; ++i) {
    int row = bm + ty * 4 + i;
    if (row >= M) continue;
    #pragma unroll
    for (int j = 0; j < 4; ++j) {
      int col = bn + tx * 4 + j;
      if (col >= N) continue;
      float v = acc[i][j];
      if (bias) v += bias[col];
      if (ACT == 1) v = fmaxf(v, 0.0f) + log1pf(expf(-fabsf(v)));
      Cm[(size_t)row * N + col] = v;
    }
  }
}

// ---------------- xproj split-K partials: part[kc][M][80] = xc * xproj_w (K-chunk) --------
__global__ __launch_bounds__(256) void xproj_kernel(const float* __restrict__ xc,
    const float* __restrict__ w, float* __restrict__ part) {
  __shared__ float at[64][44];
  __shared__ float wt[32][80];
  int kc = blockIdx.x, mt = blockIdx.y;
  int t = threadIdx.x;
  int tx = t & 15, ty = t >> 4;
  float acc[4][5] = {};
  int sr = t >> 3, sc4 = (t & 7) * 4;
  for (int k0 = kc * 192; k0 < kc * 192 + 192; k0 += 32) {
    __syncthreads();
    float4 v0 = *reinterpret_cast<const float4*>(xc + (size_t)(mt * 64 + sr) * NIN + k0 + sc4);
    float4 v1 = *reinterpret_cast<const float4*>(xc + (size_t)(mt * 64 + sr + 32) * NIN + k0 + sc4);
    *reinterpret_cast<float4*>(&at[sr][sc4])      = v0;
    *reinterpret_cast<float4*>(&at[sr + 32][sc4]) = v1;
    for (int i = t; i < 32 * 80; i += 256)
      wt[i / 80][i % 80] = w[(size_t)(k0 + i / 80) * 80 + i % 80];
    __syncthreads();
    #pragma unroll
    for (int kk = 0; kk < 32; ++kk) {
      float a0[4], b0[5];
      #pragma unroll
      for (int i = 0; i < 4; ++i) a0[i] = at[ty * 4 + i][kk];
      #pragma unroll
      for (int j = 0; j < 5; ++j) b0[j] = wt[kk][tx + 16 * j];
      #pragma unroll
      for (int i = 0; i < 4; ++i)
        #pragma unroll
        for (int j = 0; j < 5; ++j)
          acc[i][j] = fmaf(a0[i], b0[j], acc[i][j]);
    }
  }
  #pragma unroll
  for (int i = 0; i < 4; ++i)
    #pragma unroll
    for (int j = 0; j < 5; ++j)
      part[((size_t)kc * Mn + mt * 64 + ty * 4 + i) * 80 + tx + 16 * j] = acc[i][j];
}

__global__ __launch_bounds__(256) void xpred_kernel(const float* __restrict__ part,
                                                    float* __restrict__ dbc) {
  int i = blockIdx.x * 256 + threadIdx.x;   // Mn*80 = 92160 = 360*256
  float s = 0.f;
  #pragma unroll
  for (int kc = 0; kc < 8; ++kc) s += part[(size_t)kc * (Mn * 80) + i];
  dbc[i] = s;
}

// ---------------- LayerNorm over 768, writes bf16-split h ----------------
__global__ __launch_bounds__(256) void ln_kernel(const float* __restrict__ in,
    const float* __restrict__ g, const float* __restrict__ be,
    unsigned short* __restrict__ hhi, unsigned short* __restrict__ hlo) {
  int row = blockIdx.x;
  const float* r = in + (size_t)row * HID;
  int t = threadIdx.x;
  float v0 = r[t], v1 = r[t + 256], v2 = r[t + 512];
  float s  = v0 + v1 + v2;
  float s2 = v0 * v0 + v1 * v1 + v2 * v2;
  #pragma unroll
  for (int o = 32; o > 0; o >>= 1) {
    s  += __shfl_down(s,  o, 64);
    s2 += __shfl_down(s2, o, 64);
  }
  __shared__ float red[8];
  int wid = t >> 6, lane = t & 63;
  if (lane == 0) { red[wid] = s; red[4 + wid] = s2; }
  __syncthreads();
  float S  = red[0] + red[1] + red[2] + red[3];
  float S2 = red[4] + red[5] + red[6] + red[7];
  float mu  = S * (1.0f / HID);
  float var = S2 * (1.0f / HID) - mu * mu;
  float inv = rsqrtf(var + 1e-5f);
  #pragma unroll
  for (int q = 0; q < 3; ++q) {
    int c = t + q * 256;
    float v = (q == 0 ? v0 : (q == 1 ? v1 : v2));
    float hv = (v - mu) * inv * g[c] + be[c];
    unsigned short hi, lo;
    split_bf(hv, hi, lo);
    size_t o = (size_t)row * HID + c;
    hhi[o] = hi; hlo[o] = lo;
  }
}

// ---------------- depthwise conv (k=3) + silu ----------------
__global__ __launch_bounds__(256) void conv_silu_kernel(const float* __restrict__ xz,
    const float* __restrict__ w, const float* __restrict__ cb, float* __restrict__ xc) {
  int idx = blockIdx.x * 256 + threadIdx.x;
  if (idx >= Mn * NIN) return;
  int d  = idx % NIN;
  int bp = idx / NIN;
  int p = bp % Ln, b = bp / Ln;
  const float* base = xz + (size_t)(b * Ln) * (2 * NIN) + d;
  float acc = cb[d];
  float w0 = w[d * 3], w1 = w[d * 3 + 1], w2 = w[d * 3 + 2];
  if (p > 0)      acc += base[(size_t)(p - 1) * (2 * NIN)] * w0;
  acc += base[(size_t)p * (2 * NIN)] * w1;
  if (p < Ln - 1) acc += base[(size_t)(p + 1) * (2 * NIN)] * w2;
  float sg = 1.0f / (1.0f + expf(-acc));
  xc[idx] = acc * sg;
}

// ---------------- selective scan + D-residual + z-gate, writes bf16-split ya ----------------
__global__ __launch_bounds__(256) void scan_kernel(const float* __restrict__ delta,
    const float* __restrict__ dbc, const float* __restrict__ xcb,
    const float* __restrict__ A_log, const float* __restrict__ Dp,
    const float* __restrict__ xz,
    unsigned short* __restrict__ yhi, unsigned short* __restrict__ ylo) {
  __shared__ float Bsh[Ln][NST], Csh[Ln][NST];
  int b      = blockIdx.x / (NIN / 256);
  int dchunk = blockIdx.x % (NIN / 256);
  int t = threadIdx.x;
  if (t < Ln * NST) {
    int p = t / NST, n = t % NST;
    const float* row = dbc + (size_t)(b * Ln + p) * (DTR + 2 * NST);
    Bsh[p][n] = row[DTR + n];
    Csh[p][n] = row[DTR + NST + n];
  }
  __syncthreads();
  int d = dchunk * 256 + t;
  float Ar[NST];
  #pragma unroll
  for (int n = 0; n < NST; ++n) Ar[n] = -expf(A_log[(size_t)d * NST + n]);
  float s[NST];
  #pragma unroll
  for (int n = 0; n < NST; ++n) s[n] = 0.0f;
  float Dv = Dp[d];
  for (int p = 0; p < Ln; ++p) {
    size_t off = (size_t)(b * Ln + p) * NIN + d;
    float dl = delta[off];
    float u  = xcb[off];
    float du = dl * u;
    float y = 0.0f;
    #pragma unroll
    for (int n = 0; n < NST; ++n) {
      float dA = expf(dl * Ar[n]);
      s[n] = dA * s[n] + du * Bsh[p][n];
      y += s[n] * Csh[p][n];
    }
    float zv = xz[(size_t)(b * Ln + p) * (2 * NIN) + NIN + d];
    float sz = zv / (1.0f + expf(-zv));
    float yv = (y + u * Dv) * sz;
    unsigned short hi, lo;
    split_bf(yv, hi, lo);
    yhi[off] = hi; ylo[off] = lo;
  }
}

// ---------------- transpose + bilinear resize (3,3) -> (24,12) ----------------
__global__ __launch_bounds__(256) void resize_kernel(const float* __restrict__ o9,
                                                     float* __restrict__ out) {
  int idx = blockIdx.x * 256 + threadIdx.x;
  if (idx >= Bn * Cn * Hn) return;
  int y  = idx % Hn;
  int bc = idx / Hn;
  int c = bc % Cn, b = bc / Cn;
  float v[9];
  #pragma unroll
  for (int p = 0; p < 9; ++p) v[p] = o9[(size_t)(b * Ln + p) * Cn + c];
  float fy  = (y + 0.5f) * 0.125f - 0.5f;
  float fyf = floorf(fy);
  float wy  = fy - fyf;
  int y0 = (int)fyf, y1 = y0 + 1;
  y0 = min(2, max(0, y0)); y1 = min(2, max(0, y1));
  float rr[3];
  #pragma unroll
  for (int j = 0; j < 3; ++j) rr[j] = v[y0 * 3 + j] * (1.0f - wy) + v[y1 * 3 + j] * wy;
  float ov[12];
  #pragma unroll
  for (int xo = 0; xo < 12; ++xo) {
    float fx  = (xo + 0.5f) * 0.25f - 0.5f;
    float fxf = floorf(fx);
    float wx  = fx - fxf;
    int x0 = (int)fxf, x1 = x0 + 1;
    x0 = min(2, max(0, x0)); x1 = min(2, max(0, x1));
    ov[xo] = rr[x0] * (1.0f - wx) + rr[x1] * wx;
  }
  float4* op = reinterpret_cast<float4*>(out + (size_t)idx * 12);
  op[0] = make_float4(ov[0], ov[1], ov[2],  ov[3]);
  op[1] = make_float4(ov[4], ov[5], ov[6],  ov[7]);
  op[2] = make_float4(ov[8], ov[9], ov[10], ov[11]);
}

extern "C" void kernel_launch(void* const* d_in, const int* in_sizes, int n_in,
                              void* d_out, int out_size, void* d_ws, size_t ws_size,
                              hipStream_t stream) {
  const float* x        = (const float*)d_in[0];
  const float* pe_w     = (const float*)d_in[1];
  const float* pe_b     = (const float*)d_in[2];
  const float* ln_g     = (const float*)d_in[3];
  const float* ln_b     = (const float*)d_in[4];
  const float* in_w     = (const float*)d_in[5];
  const float* conv_w   = (const float*)d_in[6];
  const float* conv_b   = (const float*)d_in[7];
  const float* A_log    = (const float*)d_in[8];
  const float* xproj_w  = (const float*)d_in[9];
  const float* dtproj_w = (const float*)d_in[10];
  const float* dtproj_b = (const float*)d_in[11];
  const float* D_param  = (const float*)d_in[12];
  const float* out_w    = (const float*)d_in[13];
  float* out = (float*)d_out;
  char* ws = (char*)d_ws;

  size_t o = 0;
  auto alloc = [&](size_t bytes) { size_t r = o; o += (bytes + 255) & ~(size_t)255; return r; };
  unsigned short* tok_hi = (unsigned short*)(ws + alloc((size_t)Mn * Cn * 2));
  unsigned short* tok_lo = (unsigned short*)(ws + alloc((size_t)Mn * Cn * 2));
  unsigned short* peT_hi = (unsigned short*)(ws + alloc((size_t)HID * Cn * 2));
  unsigned short* peT_lo = (unsigned short*)(ws + alloc((size_t)HID * Cn * 2));
  float*          t1     = (float*)(ws + alloc((size_t)Mn * HID * 4));
  unsigned short* inT_hi = (unsigned short*)(ws + alloc((size_t)2 * NIN * HID * 2));
  unsigned short* inT_lo = (unsigned short*)(ws + alloc((size_t)2 * NIN * HID * 2));
  unsigned short* h_hi   = (unsigned short*)(ws + alloc((size_t)Mn * HID * 2));
  unsigned short* h_lo   = (unsigned short*)(ws + alloc((size_t)Mn * HID * 2));
  float*          xz     = (float*)(ws + alloc((size_t)Mn * 2 * NIN * 4));
  float*          xc     = (float*)(ws + alloc((size_t)Mn * NIN * 4));
  float*          dbc    = (float*)(ws + alloc((size_t)Mn * (DTR + 2 * NST) * 4));
  float*          delta  = (float*)(ws + alloc((size_t)Mn * NIN * 4));
  unsigned short* outT_hi= (unsigned short*)(ws + alloc((size_t)Cn * NIN * 2));
  unsigned short* outT_lo= (unsigned short*)(ws + alloc((size_t)Cn * NIN * 2));
  unsigned short* ya_hi  = (unsigned short*)(ws + alloc((size_t)Mn * NIN * 2));
  unsigned short* ya_lo  = (unsigned short*)(ws + alloc((size_t)Mn * NIN * 2));
  float*          o9     = (float*)(ws + alloc((size_t)Mn * Cn * 4));
  float*          part   = (float*)(ws + alloc((size_t)8 * Mn * 80 * 4));

  // weight conversions (independent of activations)
  tconv_kernel<<<dim3(HID / 32, Cn / 32), 256, 0, stream>>>(pe_w, Cn, HID, peT_hi, peT_lo);
  tconv_kernel<<<dim3(2 * NIN / 32, HID / 32), 256, 0, stream>>>(in_w, HID, 2 * NIN, inT_hi, inT_lo);
  tconv_kernel<<<dim3(Cn / 32, NIN / 32), 256, 0, stream>>>(out_w, NIN, Cn, outT_hi, outT_lo);

  pool_kernel<<<(Bn * Cn) / 256, 256, 0, stream>>>(x, tok_hi, tok_lo);
  mgemm_kernel<1><<<dim3(HID / 64, Mn / 64), 256, 0, stream>>>(
      tok_hi, tok_lo, peT_hi, peT_lo, pe_b, t1, Mn, HID, Cn);
  ln_kernel<<<Mn, 256, 0, stream>>>(t1, ln_g, ln_b, h_hi, h_lo);
  mgemm_kernel<0><<<dim3(2 * NIN / 64, Mn / 64), 256, 0, stream>>>(
      h_hi, h_lo, inT_hi, inT_lo, nullptr, xz, Mn, 2 * NIN, HID);
  conv_silu_kernel<<<(Mn * NIN) / 256, 256, 0, stream>>>(xz, conv_w, conv_b, xc);
  xproj_kernel<<<dim3(8, Mn / 64), 256, 0, stream>>>(xc, xproj_w, part);
  xpred_kernel<<<(Mn * 80) / 256, 256, 0, stream>>>(part, dbc);
  gemm_kernel<1><<<dim3(NIN / 64, Mn / 64), 256, 0, stream>>>(
      dbc, DTR + 2 * NST, dtproj_w, dtproj_b, delta, Mn, NIN, DTR);
  scan_kernel<<<Bn * (NIN / 256), 256, 0, stream>>>(
      delta, dbc, xc, A_log, D_param, xz, ya_hi, ya_lo);
  mgemm_kernel<0><<<dim3(Cn / 64, Mn / 64), 256, 0, stream>>>(
      ya_hi, ya_lo, outT_hi, outT_lo, nullptr, o9, Mn, Cn, NIN);
  resize_kernel<<<(Bn * Cn * Hn) / 256, 256, 0, stream>>>(o9, out);
}

// Round 4
// 532.850 us; speedup vs baseline: 1.2411x; 1.2411x over previous
//
#include <hip/hip_runtime.h>
#include <math.h>

#define Bn   128
#define Cn   2048
#define Hn   24
#define Wn   12
#define HID  768
#define NIN  1536
#define NST  16
#define DTR  48
#define Ln   9
#define Mn   (Bn*Ln)   // 1152

typedef __bf16 bf16x8 __attribute__((ext_vector_type(8)));
typedef float  f32x4  __attribute__((ext_vector_type(4)));

__device__ __forceinline__ unsigned short f2bf(float f) {
  unsigned u = __float_as_uint(f);
  u += 0x7fffu + ((u >> 16) & 1u);           // round-to-nearest-even
  return (unsigned short)(u >> 16);
}
__device__ __forceinline__ float bf2f(unsigned short h) {
  return __uint_as_float(((unsigned)h) << 16);
}
__device__ __forceinline__ void split_bf(float f, unsigned short& hi, unsigned short& lo) {
  hi = f2bf(f);
  lo = f2bf(f - bf2f(hi));
}
// interleaved hi/lo column index: per 32-k block, [hi 0..31 | lo 0..31]
__device__ __forceinline__ int col2(int k) { return ((k >> 5) << 6) + (k & 31); }

// ---------------- pooling: x (B,C,24,12) -> tok2 (B*9, 2*C) interleaved hi/lo ----------------
__global__ __launch_bounds__(256) void pool_kernel(const float* __restrict__ x,
    unsigned short* __restrict__ tok2) {
  int idx = blockIdx.x * 256 + threadIdx.x;           // over B*C
  if (idx >= Bn * Cn) return;
  int b = idx / Cn, c = idx - b * Cn;
  const float4* p = reinterpret_cast<const float4*>(x + (size_t)idx * (Hn * Wn));
  float s[9] = {0,0,0,0,0,0,0,0,0};
  #pragma unroll
  for (int h = 0; h < 24; ++h) {
    int i = h >> 3;
    #pragma unroll
    for (int j = 0; j < 3; ++j) {
      float4 v = p[h * 3 + j];
      s[i * 3 + j] += (v.x + v.y) + (v.z + v.w);
    }
  }
  int cc = col2(c);
  #pragma unroll
  for (int pp = 0; pp < 9; ++pp) {
    float v = s[pp] * (1.0f / 32.0f);
    unsigned short hi, lo;
    split_bf(v, hi, lo);
    size_t base = ((size_t)(b * Ln + pp)) * (2 * Cn) + cc;
    tok2[base] = hi; tok2[base + 32] = lo;
  }
}

// ---------------- fp32 W[K][N] -> transposed interleaved T2[N][2K] ----------------
__global__ __launch_bounds__(256) void tconv_kernel(const float* __restrict__ W,
    int K, int N, unsigned short* __restrict__ T2) {
  __shared__ float tile[32][33];
  int nb = blockIdx.x, kb = blockIdx.y;
  int t = threadIdx.x;
  int kl = t >> 3, n4 = (t & 7) * 4;
  float4 v = *reinterpret_cast<const float4*>(W + (size_t)(kb * 32 + kl) * N + nb * 32 + n4);
  tile[kl][n4] = v.x; tile[kl][n4 + 1] = v.y; tile[kl][n4 + 2] = v.z; tile[kl][n4 + 3] = v.w;
  __syncthreads();
  int nl = t >> 3, k4 = (t & 7) * 4;                  // k4 in [0,32), 4-aligned
  unsigned short hi[4], lo[4];
  #pragma unroll
  for (int i = 0; i < 4; ++i) split_bf(tile[k4 + i][nl], hi[i], lo[i]);
  // global k = kb*32 + k4 (+0..3): col2 = kb*64 + k4 (hi), +32 (lo)
  size_t base = (size_t)(nb * 32 + nl) * (2 * K) + kb * 64 + k4;
  uint2 ph, pl;
  ph.x = (unsigned)hi[0] | ((unsigned)hi[1] << 16);
  ph.y = (unsigned)hi[2] | ((unsigned)hi[3] << 16);
  pl.x = (unsigned)lo[0] | ((unsigned)lo[1] << 16);
  pl.y = (unsigned)lo[2] | ((unsigned)lo[3] << 16);
  *reinterpret_cast<uint2*>(T2 + base)      = ph;
  *reinterpret_cast<uint2*>(T2 + base + 32) = pl;
}

// ------------- split-bf16 MFMA GEMM: C = A(M,K) * B^T(N,K), interleaved hi/lo inputs -------------
// 128x128 tile, BK=32, 4 waves of 64x64, simple 2-barrier loop (no reg prefetch -> no spill).
// blockIdx.z = split-K chunk; Cout offset by z*M*N.
__global__ __launch_bounds__(256) void mgemm_kernel(
    const unsigned short* __restrict__ A2, const unsigned short* __restrict__ B2,
    float* __restrict__ Cout, int M, int N, int K, int Ksub) {
  __shared__ unsigned short As[128][64];
  __shared__ unsigned short Bs[128][64];
  int t = threadIdx.x;
  int bm = blockIdx.y * 128, bn = blockIdx.x * 128;
  int ksI = blockIdx.z;
  int wave = t >> 6, lane = t & 63;
  int wr = (wave >> 1) * 64, wc = (wave & 1) * 64;
  int lr = lane & 15, lk = lane >> 4;

  const unsigned short* Ag[4];
  const unsigned short* Bg[4];
  unsigned short* Alp[4];
  unsigned short* Blp[4];
  #pragma unroll
  for (int i = 0; i < 4; ++i) {
    int cid = t + i * 256;
    int row = cid >> 3, c = cid & 7;
    int pc = c ^ (row & 7);
    size_t koff = (size_t)ksI * (2 * Ksub) + c * 8;
    Ag[i] = A2 + (size_t)(bm + row) * (2 * K) + koff;
    Bg[i] = B2 + (size_t)(bn + row) * (2 * K) + koff;
    Alp[i] = &As[row][pc * 8];
    Blp[i] = &Bs[row][pc * 8];
  }

  f32x4 acc[4][4];
  #pragma unroll
  for (int m = 0; m < 4; ++m)
    #pragma unroll
    for (int n = 0; n < 4; ++n) acc[m][n] = {0.f, 0.f, 0.f, 0.f};

  for (int kk = 0; kk < Ksub; kk += 32) {
    float4 va[4], vb[4];
    #pragma unroll
    for (int i = 0; i < 4; ++i) {
      va[i] = *reinterpret_cast<const float4*>(Ag[i] + kk * 2);
      vb[i] = *reinterpret_cast<const float4*>(Bg[i] + kk * 2);
    }
    __syncthreads();   // previous iteration's fragment reads complete
    #pragma unroll
    for (int i = 0; i < 4; ++i) {
      *reinterpret_cast<float4*>(Alp[i]) = va[i];
      *reinterpret_cast<float4*>(Blp[i]) = vb[i];
    }
    __syncthreads();

    bf16x8 ah[4], al[4], bh[4], bl[4];
    #pragma unroll
    for (int m = 0; m < 4; ++m) {
      int ar = wr + m * 16 + lr;
      ah[m] = *reinterpret_cast<const bf16x8*>(&As[ar][((lk    ) ^ (ar & 7)) * 8]);
      al[m] = *reinterpret_cast<const bf16x8*>(&As[ar][((4 + lk) ^ (ar & 7)) * 8]);
    }
    #pragma unroll
    for (int n = 0; n < 4; ++n) {
      int br = wc + n * 16 + lr;
      bh[n] = *reinterpret_cast<const bf16x8*>(&Bs[br][((lk    ) ^ (br & 7)) * 8]);
      bl[n] = *reinterpret_cast<const bf16x8*>(&Bs[br][((4 + lk) ^ (br & 7)) * 8]);
    }
    #pragma unroll
    for (int m = 0; m < 4; ++m)
      #pragma unroll
      for (int n = 0; n < 4; ++n) {
        acc[m][n] = __builtin_amdgcn_mfma_f32_16x16x32_bf16(ah[m], bh[n], acc[m][n], 0, 0, 0);
        acc[m][n] = __builtin_amdgcn_mfma_f32_16x16x32_bf16(ah[m], bl[n], acc[m][n], 0, 0, 0);
        acc[m][n] = __builtin_amdgcn_mfma_f32_16x16x32_bf16(al[m], bh[n], acc[m][n], 0, 0, 0);
      }
  }

  float* dst = Cout + (size_t)ksI * M * N;
  #pragma unroll
  for (int m = 0; m < 4; ++m)
    #pragma unroll
    for (int n = 0; n < 4; ++n) {
      int col = bn + wc + n * 16 + lr;
      #pragma unroll
      for (int r = 0; r < 4; ++r) {
        int row = bm + wr + m * 16 + lk * 4 + r;
        dst[(size_t)row * N + col] = acc[m][n][r];
      }
    }
}

// ---------------- split-K partial reduce, optional bias ----------------
template<int KS, int BIAS>
__global__ __launch_bounds__(256) void red_kernel(const float* __restrict__ part,
    const float* __restrict__ bias, float* __restrict__ out, int MN, int N) {
  int i = blockIdx.x * 256 + threadIdx.x;
  if (i >= MN) return;
  float s = 0.f;
  #pragma unroll
  for (int ks = 0; ks < KS; ++ks) s += part[(size_t)ks * MN + i];
  if (BIAS) s += bias[i % N];
  out[i] = s;
}

// ---------------- generic fp32 tiled GEMM (dtproj only) ----------------
template<int ACT>
__global__ __launch_bounds__(256) void gemm_kernel(const float* __restrict__ A, int lda,
    const float* __restrict__ Bm, const float* __restrict__ bias, float* __restrict__ Cm,
    int M, int N, int K) {
  __shared__ float As[16][68];
  __shared__ float Bs[16][68];
  int t  = threadIdx.x;
  int bm = blockIdx.y * 64, bn = blockIdx.x * 64;
  int tx = t & 15, ty = t >> 4;
  float acc[4][4] = {};
  int ar = t >> 2, ak = (t & 3) * 4;
  int br = t >> 4, bc = (t & 15) * 4;
  for (int k0 = 0; k0 < K; k0 += 16) {
    float4 av = make_float4(0.f, 0.f, 0.f, 0.f);
    if (bm + ar < M)
      av = *reinterpret_cast<const float4*>(A + (size_t)(bm + ar) * lda + k0 + ak);
    As[ak + 0][ar] = av.x; As[ak + 1][ar] = av.y;
    As[ak + 2][ar] = av.z; As[ak + 3][ar] = av.w;
    float4 bv = make_float4(0.f, 0.f, 0.f, 0.f);
    if (bn + bc < N)
      bv = *reinterpret_cast<const float4*>(Bm + (size_t)(k0 + br) * N + bn + bc);
    *reinterpret_cast<float4*>(&Bs[br][bc]) = bv;
    __syncthreads();
    #pragma unroll
    for (int kk = 0; kk < 16; ++kk) {
      float a0[4], b0[4];
      #pragma unroll
      for (int i = 0; i < 4; ++i) a0[i] = As[kk][ty * 4 + i];
      #pragma unroll
      for (int j = 0; j < 4; ++j) b0[j] = Bs[kk][tx * 4 + j];
      #pragma unroll
      for (int i = 0; i < 4; ++i)
        #pragma unroll
        for (int j = 0; j < 4; ++j)
          acc[i][j] = fmaf(a0[i], b0[j], acc[i][j]);
    }
    __syncthreads();
  }
  #pragma unroll
  for (int i = 0; i < 4; ++i) {
    int row = bm + ty * 4 + i;
    if (row >= M) continue;
    #pragma unroll
    for (int j = 0; j < 4; ++j) {
      int col = bn + tx * 4 + j;
      if (col >= N) continue;
      float v = acc[i][j];
      if (bias) v += bias[col];
      if (ACT == 1) v = fmaxf(v, 0.0f) + log1pf(expf(-fabsf(v)));
      Cm[(size_t)row * N + col] = v;
    }
  }
}

// ---------------- xproj split-K partials ----------------
__global__ __launch_bounds__(256) void xproj_kernel(const float* __restrict__ xc,
    const float* __restrict__ w, float* __restrict__ part) {
  __shared__ float at[64][44];
  __shared__ float wt[32][80];
  int kc = blockIdx.x, mt = blockIdx.y;
  int t = threadIdx.x;
  int tx = t & 15, ty = t >> 4;
  float acc[4][5] = {};
  int sr = t >> 3, sc4 = (t & 7) * 4;
  for (int k0 = kc * 192; k0 < kc * 192 + 192; k0 += 32) {
    __syncthreads();
    float4 v0 = *reinterpret_cast<const float4*>(xc + (size_t)(mt * 64 + sr) * NIN + k0 + sc4);
    float4 v1 = *reinterpret_cast<const float4*>(xc + (size_t)(mt * 64 + sr + 32) * NIN + k0 + sc4);
    *reinterpret_cast<float4*>(&at[sr][sc4])      = v0;
    *reinterpret_cast<float4*>(&at[sr + 32][sc4]) = v1;
    for (int i = t; i < 32 * 80; i += 256)
      wt[i / 80][i % 80] = w[(size_t)(k0 + i / 80) * 80 + i % 80];
    __syncthreads();
    #pragma unroll
    for (int kk = 0; kk < 32; ++kk) {
      float a0[4], b0[5];
      #pragma unroll
      for (int i = 0; i < 4; ++i) a0[i] = at[ty * 4 + i][kk];
      #pragma unroll
      for (int j = 0; j < 5; ++j) b0[j] = wt[kk][tx + 16 * j];
      #pragma unroll
      for (int i = 0; i < 4; ++i)
        #pragma unroll
        for (int j = 0; j < 5; ++j)
          acc[i][j] = fmaf(a0[i], b0[j], acc[i][j]);
    }
  }
  #pragma unroll
  for (int i = 0; i < 4; ++i)
    #pragma unroll
    for (int j = 0; j < 5; ++j)
      part[((size_t)kc * Mn + mt * 64 + ty * 4 + i) * 80 + tx + 16 * j] = acc[i][j];
}

__global__ __launch_bounds__(256) void xpred_kernel(const float* __restrict__ part,
                                                    float* __restrict__ dbc) {
  int i = blockIdx.x * 256 + threadIdx.x;   // Mn*80 = 92160 = 360*256
  float s = 0.f;
  #pragma unroll
  for (int kc = 0; kc < 8; ++kc) s += part[(size_t)kc * (Mn * 80) + i];
  dbc[i] = s;
}

// ---------------- LayerNorm over 768, writes interleaved h2 ----------------
__global__ __launch_bounds__(256) void ln_kernel(const float* __restrict__ in,
    const float* __restrict__ g, const float* __restrict__ be,
    unsigned short* __restrict__ h2) {
  int row = blockIdx.x;
  const float* r = in + (size_t)row * HID;
  int t = threadIdx.x;
  float v0 = r[t], v1 = r[t + 256], v2 = r[t + 512];
  float s  = v0 + v1 + v2;
  float s2 = v0 * v0 + v1 * v1 + v2 * v2;
  #pragma unroll
  for (int o = 32; o > 0; o >>= 1) {
    s  += __shfl_down(s,  o, 64);
    s2 += __shfl_down(s2, o, 64);
  }
  __shared__ float red[8];
  int wid = t >> 6, lane = t & 63;
  if (lane == 0) { red[wid] = s; red[4 + wid] = s2; }
  __syncthreads();
  float S  = red[0] + red[1] + red[2] + red[3];
  float S2 = red[4] + red[5] + red[6] + red[7];
  float mu  = S * (1.0f / HID);
  float var = S2 * (1.0f / HID) - mu * mu;
  float inv = rsqrtf(var + 1e-5f);
  #pragma unroll
  for (int q = 0; q < 3; ++q) {
    int c = t + q * 256;
    float v = (q == 0 ? v0 : (q == 1 ? v1 : v2));
    float hv = (v - mu) * inv * g[c] + be[c];
    unsigned short hi, lo;
    split_bf(hv, hi, lo);
    size_t base = (size_t)row * (2 * HID) + col2(c);
    h2[base] = hi; h2[base + 32] = lo;
  }
}

// ---------------- depthwise conv (k=3) + silu ----------------
__global__ __launch_bounds__(256) void conv_silu_kernel(const float* __restrict__ xz,
    const float* __restrict__ w, const float* __restrict__ cb, float* __restrict__ xc) {
  int idx = blockIdx.x * 256 + threadIdx.x;
  if (idx >= Mn * NIN) return;
  int d  = idx % NIN;
  int bp = idx / NIN;
  int p = bp % Ln, b = bp / Ln;
  const float* base = xz + (size_t)(b * Ln) * (2 * NIN) + d;
  float acc = cb[d];
  float w0 = w[d * 3], w1 = w[d * 3 + 1], w2 = w[d * 3 + 2];
  if (p > 0)      acc += base[(size_t)(p - 1) * (2 * NIN)] * w0;
  acc += base[(size_t)p * (2 * NIN)] * w1;
  if (p < Ln - 1) acc += base[(size_t)(p + 1) * (2 * NIN)] * w2;
  float sg = 1.0f / (1.0f + expf(-acc));
  xc[idx] = acc * sg;
}

// ---------------- selective scan + D-residual + z-gate, writes interleaved ya2 ----------------
__global__ __launch_bounds__(256) void scan_kernel(const float* __restrict__ delta,
    const float* __restrict__ dbc, const float* __restrict__ xcb,
    const float* __restrict__ A_log, const float* __restrict__ Dp,
    const float* __restrict__ xz, unsigned short* __restrict__ ya2) {
  __shared__ float Bsh[Ln][NST], Csh[Ln][NST];
  int b      = blockIdx.x / (NIN / 256);
  int dchunk = blockIdx.x % (NIN / 256);
  int t = threadIdx.x;
  if (t < Ln * NST) {
    int p = t / NST, n = t % NST;
    const float* row = dbc + (size_t)(b * Ln + p) * (DTR + 2 * NST);
    Bsh[p][n] = row[DTR + n];
    Csh[p][n] = row[DTR + NST + n];
  }
  __syncthreads();
  int d = dchunk * 256 + t;
  float Ar[NST];
  #pragma unroll
  for (int n = 0; n < NST; ++n) Ar[n] = -expf(A_log[(size_t)d * NST + n]);
  float s[NST];
  #pragma unroll
  for (int n = 0; n < NST; ++n) s[n] = 0.0f;
  float Dv = Dp[d];
  int cc = col2(d);
  for (int p = 0; p < Ln; ++p) {
    size_t off = (size_t)(b * Ln + p) * NIN + d;
    float dl = delta[off];
    float u  = xcb[off];
    float du = dl * u;
    float y = 0.0f;
    #pragma unroll
    for (int n = 0; n < NST; ++n) {
      float dA = expf(dl * Ar[n]);
      s[n] = dA * s[n] + du * Bsh[p][n];
      y += s[n] * Csh[p][n];
    }
    float zv = xz[(size_t)(b * Ln + p) * (2 * NIN) + NIN + d];
    float sz = zv / (1.0f + expf(-zv));
    float yv = (y + u * Dv) * sz;
    unsigned short hi, lo;
    split_bf(yv, hi, lo);
    size_t base = (size_t)(b * Ln + p) * (2 * NIN) + cc;
    ya2[base] = hi; ya2[base + 32] = lo;
  }
}

// ---------------- transpose + bilinear resize (3,3) -> (24,12) ----------------
__global__ __launch_bounds__(256) void resize_kernel(const float* __restrict__ o9,
                                                     float* __restrict__ out) {
  int idx = blockIdx.x * 256 + threadIdx.x;
  if (idx >= Bn * Cn * Hn) return;
  int y  = idx % Hn;
  int bc = idx / Hn;
  int c = bc % Cn, b = bc / Cn;
  float v[9];
  #pragma unroll
  for (int p = 0; p < 9; ++p) v[p] = o9[(size_t)(b * Ln + p) * Cn + c];
  float fy  = (y + 0.5f) * 0.125f - 0.5f;
  float fyf = floorf(fy);
  float wy  = fy - fyf;
  int y0 = (int)fyf, y1 = y0 + 1;
  y0 = min(2, max(0, y0)); y1 = min(2, max(0, y1));
  float rr[3];
  #pragma unroll
  for (int j = 0; j < 3; ++j) rr[j] = v[y0 * 3 + j] * (1.0f - wy) + v[y1 * 3 + j] * wy;
  float ov[12];
  #pragma unroll
  for (int xo = 0; xo < 12; ++xo) {
    float fx  = (xo + 0.5f) * 0.25f - 0.5f;
    float fxf = floorf(fx);
    float wx  = fx - fxf;
    int x0 = (int)fxf, x1 = x0 + 1;
    x0 = min(2, max(0, x0)); x1 = min(2, max(0, x1));
    ov[xo] = rr[x0] * (1.0f - wx) + rr[x1] * wx;
  }
  float4* op = reinterpret_cast<float4*>(out + (size_t)idx * 12);
  op[0] = make_float4(ov[0], ov[1], ov[2],  ov[3]);
  op[1] = make_float4(ov[4], ov[5], ov[6],  ov[7]);
  op[2] = make_float4(ov[8], ov[9], ov[10], ov[11]);
}

extern "C" void kernel_launch(void* const* d_in, const int* in_sizes, int n_in,
                              void* d_out, int out_size, void* d_ws, size_t ws_size,
                              hipStream_t stream) {
  const float* x        = (const float*)d_in[0];
  const float* pe_w     = (const float*)d_in[1];
  const float* pe_b     = (const float*)d_in[2];
  const float* ln_g     = (const float*)d_in[3];
  const float* ln_b     = (const float*)d_in[4];
  const float* in_w     = (const float*)d_in[5];
  const float* conv_w   = (const float*)d_in[6];
  const float* conv_b   = (const float*)d_in[7];
  const float* A_log    = (const float*)d_in[8];
  const float* xproj_w  = (const float*)d_in[9];
  const float* dtproj_w = (const float*)d_in[10];
  const float* dtproj_b = (const float*)d_in[11];
  const float* D_param  = (const float*)d_in[12];
  const float* out_w    = (const float*)d_in[13];
  float* out = (float*)d_out;
  char* ws = (char*)d_ws;

  size_t o = 0;
  auto alloc = [&](size_t bytes) { size_t r = o; o += (bytes + 255) & ~(size_t)255; return r; };
  unsigned short* tok2  = (unsigned short*)(ws + alloc((size_t)Mn * 2 * Cn * 2));
  unsigned short* peT2  = (unsigned short*)(ws + alloc((size_t)HID * 2 * Cn * 2));
  unsigned short* inT2  = (unsigned short*)(ws + alloc((size_t)2 * NIN * 2 * HID * 2));
  unsigned short* outT2 = (unsigned short*)(ws + alloc((size_t)Cn * 2 * NIN * 2));
  unsigned short* h2    = (unsigned short*)(ws + alloc((size_t)Mn * 2 * HID * 2));
  unsigned short* ya2   = (unsigned short*)(ws + alloc((size_t)Mn * 2 * NIN * 2));
  float* t1    = (float*)(ws + alloc((size_t)Mn * HID * 4));
  float* xz    = (float*)(ws + alloc((size_t)Mn * 2 * NIN * 4));
  float* xc    = (float*)(ws + alloc((size_t)Mn * NIN * 4));
  float* dbc   = (float*)(ws + alloc((size_t)Mn * 80 * 4));
  float* delta = (float*)(ws + alloc((size_t)Mn * NIN * 4));
  float* o9    = (float*)(ws + alloc((size_t)Mn * Cn * 4));
  float* part1 = (float*)(ws + alloc((size_t)4 * Mn * HID * 4));
  float* part3 = (float*)(ws + alloc((size_t)2 * Mn * Cn * 4));
  float* partx = (float*)(ws + alloc((size_t)8 * Mn * 80 * 4));

  // weight conversions (independent of activations)
  tconv_kernel<<<dim3(HID / 32, Cn / 32), 256, 0, stream>>>(pe_w, Cn, HID, peT2);
  tconv_kernel<<<dim3(2 * NIN / 32, HID / 32), 256, 0, stream>>>(in_w, HID, 2 * NIN, inT2);
  tconv_kernel<<<dim3(Cn / 32, NIN / 32), 256, 0, stream>>>(out_w, NIN, Cn, outT2);

  pool_kernel<<<(Bn * Cn) / 256, 256, 0, stream>>>(x, tok2);
  // tok @ pe_w : M=1152 N=768 K=2048, split-K=4
  mgemm_kernel<<<dim3(HID / 128, Mn / 128, 4), 256, 0, stream>>>(
      tok2, peT2, part1, Mn, HID, Cn, Cn / 4);
  red_kernel<4, 1><<<(Mn * HID) / 256, 256, 0, stream>>>(part1, pe_b, t1, Mn * HID, HID);
  ln_kernel<<<Mn, 256, 0, stream>>>(t1, ln_g, ln_b, h2);
  // h @ in_w : M=1152 N=3072 K=768
  mgemm_kernel<<<dim3(2 * NIN / 128, Mn / 128, 1), 256, 0, stream>>>(
      h2, inT2, xz, Mn, 2 * NIN, HID, HID);
  conv_silu_kernel<<<(Mn * NIN) / 256, 256, 0, stream>>>(xz, conv_w, conv_b, xc);
  xproj_kernel<<<dim3(8, Mn / 64), 256, 0, stream>>>(xc, xproj_w, partx);
  xpred_kernel<<<(Mn * 80) / 256, 256, 0, stream>>>(partx, dbc);
  gemm_kernel<1><<<dim3(NIN / 64, Mn / 64), 256, 0, stream>>>(
      dbc, 80, dtproj_w, dtproj_b, delta, Mn, NIN, DTR);
  scan_kernel<<<Bn * (NIN / 256), 256, 0, stream>>>(
      delta, dbc, xc, A_log, D_param, xz, ya2);
  // ya @ out_w : M=1152 N=2048 K=1536, split-K=2
  mgemm_kernel<<<dim3(Cn / 128, Mn / 128, 2), 256, 0, stream>>>(
      ya2, outT2, part3, Mn, Cn, NIN, NIN / 2);
  red_kernel<2, 0><<<(Mn * Cn) / 256, 256, 0, stream>>>(part3, nullptr, o9, Mn * Cn, Cn);
  resize_kernel<<<(Bn * Cn * Hn) / 256, 256, 0, stream>>>(o9, out);
}

// Round 5
// 364.143 us; speedup vs baseline: 1.8161x; 1.4633x over previous
//
#include <hip/hip_runtime.h>
#include <math.h>

#define Bn   128
#define Cn   2048
#define Hn   24
#define Wn   12
#define HID  768
#define NIN  1536
#define NST  16
#define DTR  48
#define Ln   9
#define Mn   (Bn*Ln)   // 1152

typedef __bf16 bf16x8 __attribute__((ext_vector_type(8)));
typedef float  f32x4  __attribute__((ext_vector_type(4)));

// async global->LDS, 16B per lane; LDS dest is wave-uniform base + lane*16
#define GLOAD16(gsrc, ldst) \
  __builtin_amdgcn_global_load_lds((const __attribute__((address_space(1))) void*)(gsrc), \
                                   (__attribute__((address_space(3))) void*)(ldst), 16, 0, 0)

__device__ __forceinline__ unsigned short f2bf(float f) {
  unsigned u = __float_as_uint(f);
  u += 0x7fffu + ((u >> 16) & 1u);           // round-to-nearest-even
  return (unsigned short)(u >> 16);
}
__device__ __forceinline__ float bf2f(unsigned short h) {
  return __uint_as_float(((unsigned)h) << 16);
}
__device__ __forceinline__ void split_bf(float f, unsigned short& hi, unsigned short& lo) {
  hi = f2bf(f);
  lo = f2bf(f - bf2f(hi));
}
// interleaved hi/lo column index: per 32-k block, [hi 0..31 | lo 0..31]
__device__ __forceinline__ int col2(int k) { return ((k >> 5) << 6) + (k & 31); }

// ---------------- pooling v2: coalesced read via LDS; 32 channels per block ----------------
__global__ __launch_bounds__(256) void pool_kernel(const float* __restrict__ x,
    unsigned short* __restrict__ tok2) {
  __shared__ float4 raw[2304];                        // 32 ch x 72 float4 = 36 KB
  int blk = blockIdx.x;                               // Bn * (Cn/32) = 8192
  int b = blk >> 6, cg = blk & 63;
  const float4* src = reinterpret_cast<const float4*>(x) + (size_t)(b * Cn + cg * 32) * 72;
  int t = threadIdx.x;
  #pragma unroll
  for (int it = 0; it < 9; ++it) raw[it * 256 + t] = src[it * 256 + t];
  __syncthreads();
  for (int cell = t; cell < 288; cell += 256) {
    int c = cell / 9, p = cell % 9, i = p / 3, j = p % 3;
    float s = 0.f;
    #pragma unroll
    for (int k = 0; k < 8; ++k) {
      float4 v = raw[c * 72 + (i * 8 + k) * 3 + j];
      s += (v.x + v.y) + (v.z + v.w);
    }
    s *= (1.0f / 32.0f);
    unsigned short hi, lo;
    split_bf(s, hi, lo);
    int cglob = cg * 32 + c;
    size_t base = ((size_t)(b * Ln + p)) * (2 * Cn) + col2(cglob);
    tok2[base] = hi; tok2[base + 32] = lo;
  }
}

// ---------------- fp32 W[K][N] -> transposed interleaved T2[N][2K] ----------------
__global__ __launch_bounds__(256) void tconv_kernel(const float* __restrict__ W,
    int K, int N, unsigned short* __restrict__ T2) {
  __shared__ float tile[32][33];
  int nb = blockIdx.x, kb = blockIdx.y;
  int t = threadIdx.x;
  int kl = t >> 3, n4 = (t & 7) * 4;
  float4 v = *reinterpret_cast<const float4*>(W + (size_t)(kb * 32 + kl) * N + nb * 32 + n4);
  tile[kl][n4] = v.x; tile[kl][n4 + 1] = v.y; tile[kl][n4 + 2] = v.z; tile[kl][n4 + 3] = v.w;
  __syncthreads();
  int nl = t >> 3, k4 = (t & 7) * 4;
  unsigned short hi[4], lo[4];
  #pragma unroll
  for (int i = 0; i < 4; ++i) split_bf(tile[k4 + i][nl], hi[i], lo[i]);
  size_t base = (size_t)(nb * 32 + nl) * (2 * K) + kb * 64 + k4;
  uint2 ph, pl;
  ph.x = (unsigned)hi[0] | ((unsigned)hi[1] << 16);
  ph.y = (unsigned)hi[2] | ((unsigned)hi[3] << 16);
  pl.x = (unsigned)lo[0] | ((unsigned)lo[1] << 16);
  pl.y = (unsigned)lo[2] | ((unsigned)lo[3] << 16);
  *reinterpret_cast<uint2*>(T2 + base)      = ph;
  *reinterpret_cast<uint2*>(T2 + base + 32) = pl;
}

// ------------- split-bf16 MFMA GEMM, global_load_lds staging with pre-swizzled source ----
// C = A(M,K)*B^T(N,K); 128x128 tile, BK=32, 4 waves of 64x64; blockIdx.z = split-K slice.
// LDS invariant: LDS[row][pc] = global[row][pc ^ (row&7)] (16B chunks).
__global__ __launch_bounds__(256) void mgemm_kernel(
    const unsigned short* __restrict__ A2, const unsigned short* __restrict__ B2,
    float* __restrict__ Cout, int M, int N, int K, int Ksub) {
  __shared__ unsigned short As[128][64];
  __shared__ unsigned short Bs[128][64];
  int t = threadIdx.x;
  int bm = blockIdx.y * 128, bn = blockIdx.x * 128;
  int wave = t >> 6, lane = t & 63;
  int wr = (wave >> 1) * 64, wc = (wave & 1) * 64;
  int lr = lane & 15, lk = lane >> 4;

  // staging: wave stages rows wave*32 .. wave*32+31 of both As and Bs (4 calls x 8 rows)
  // lane -> LDS chunk (row = base + (lane>>3), c = lane&7); row&7 == lane>>3,
  // so source chunk = (lane&7) ^ (lane>>3), lane-constant.
  int l3 = lane >> 3, c8 = lane & 7;
  int sc = c8 ^ l3;
  size_t koff = (size_t)blockIdx.z * 2 * (size_t)Ksub;
  const unsigned short* Ab = A2 + (size_t)(bm + wave * 32 + l3) * (2 * (size_t)K) + koff + sc * 8;
  const unsigned short* Bb = B2 + (size_t)(bn + wave * 32 + l3) * (2 * (size_t)K) + koff + sc * 8;
  size_t rstep = (size_t)8 * 2 * K;                   // 8 rows of global
  unsigned short* AsW = &As[wave * 32][0];
  unsigned short* BsW = &Bs[wave * 32][0];

  f32x4 acc[4][4];
  #pragma unroll
  for (int m = 0; m < 4; ++m)
    #pragma unroll
    for (int n = 0; n < 4; ++n) acc[m][n] = {0.f, 0.f, 0.f, 0.f};

  for (int kk = 0; kk < Ksub; kk += 32) {
    __syncthreads();                                  // all waves done reading LDS
    #pragma unroll
    for (int q = 0; q < 4; ++q) {
      GLOAD16(Ab + q * rstep + kk * 2, AsW + q * 8 * 64);
      GLOAD16(Bb + q * rstep + kk * 2, BsW + q * 8 * 64);
    }
    __syncthreads();                                  // drains vmcnt -> LDS ready

    bf16x8 ah[4], al[4], bh[4], bl[4];
    #pragma unroll
    for (int m = 0; m < 4; ++m) {
      int ar = wr + m * 16 + lr;
      ah[m] = *reinterpret_cast<const bf16x8*>(&As[ar][((lk    ) ^ (ar & 7)) * 8]);
      al[m] = *reinterpret_cast<const bf16x8*>(&As[ar][((4 + lk) ^ (ar & 7)) * 8]);
    }
    #pragma unroll
    for (int n = 0; n < 4; ++n) {
      int br = wc + n * 16 + lr;
      bh[n] = *reinterpret_cast<const bf16x8*>(&Bs[br][((lk    ) ^ (br & 7)) * 8]);
      bl[n] = *reinterpret_cast<const bf16x8*>(&Bs[br][((4 + lk) ^ (br & 7)) * 8]);
    }
    #pragma unroll
    for (int m = 0; m < 4; ++m)
      #pragma unroll
      for (int n = 0; n < 4; ++n) {
        acc[m][n] = __builtin_amdgcn_mfma_f32_16x16x32_bf16(ah[m], bh[n], acc[m][n], 0, 0, 0);
        acc[m][n] = __builtin_amdgcn_mfma_f32_16x16x32_bf16(ah[m], bl[n], acc[m][n], 0, 0, 0);
        acc[m][n] = __builtin_amdgcn_mfma_f32_16x16x32_bf16(al[m], bh[n], acc[m][n], 0, 0, 0);
      }
  }

  float* dst = Cout + (size_t)blockIdx.z * M * N;
  #pragma unroll
  for (int m = 0; m < 4; ++m)
    #pragma unroll
    for (int n = 0; n < 4; ++n) {
      int col = bn + wc + n * 16 + lr;
      #pragma unroll
      for (int r = 0; r < 4; ++r) {
        int row = bm + wr + m * 16 + lk * 4 + r;
        dst[(size_t)row * N + col] = acc[m][n][r];
      }
    }
}

// ---------------- split-K partial reduce ----------------
template<int KS>
__global__ __launch_bounds__(256) void red_kernel(const float* __restrict__ part,
    float* __restrict__ out, int MN) {
  int i = blockIdx.x * 256 + threadIdx.x;
  if (i >= MN) return;
  float s = 0.f;
  #pragma unroll
  for (int ks = 0; ks < KS; ++ks) s += part[(size_t)ks * MN + i];
  out[i] = s;
}

// ---------------- generic fp32 tiled GEMM (dtproj only) ----------------
template<int ACT>
__global__ __launch_bounds__(256) void gemm_kernel(const float* __restrict__ A, int lda,
    const float* __restrict__ Bm, const float* __restrict__ bias, float* __restrict__ Cm,
    int M, int N, int K) {
  __shared__ float As[16][68];
  __shared__ float Bs[16][68];
  int t  = threadIdx.x;
  int bm = blockIdx.y * 64, bn = blockIdx.x * 64;
  int tx = t & 15, ty = t >> 4;
  float acc[4][4] = {};
  int ar = t >> 2, ak = (t & 3) * 4;
  int br = t >> 4, bc = (t & 15) * 4;
  for (int k0 = 0; k0 < K; k0 += 16) {
    float4 av = make_float4(0.f, 0.f, 0.f, 0.f);
    if (bm + ar < M)
      av = *reinterpret_cast<const float4*>(A + (size_t)(bm + ar) * lda + k0 + ak);
    As[ak + 0][ar] = av.x; As[ak + 1][ar] = av.y;
    As[ak + 2][ar] = av.z; As[ak + 3][ar] = av.w;
    float4 bv = make_float4(0.f, 0.f, 0.f, 0.f);
    if (bn + bc < N)
      bv = *reinterpret_cast<const float4*>(Bm + (size_t)(k0 + br) * N + bn + bc);
    *reinterpret_cast<float4*>(&Bs[br][bc]) = bv;
    __syncthreads();
    #pragma unroll
    for (int kk = 0; kk < 16; ++kk) {
      float a0[4], b0[4];
      #pragma unroll
      for (int i = 0; i < 4; ++i) a0[i] = As[kk][ty * 4 + i];
      #pragma unroll
      for (int j = 0; j < 4; ++j) b0[j] = Bs[kk][tx * 4 + j];
      #pragma unroll
      for (int i = 0; i < 4; ++i)
        #pragma unroll
        for (int j = 0; j < 4; ++j)
          acc[i][j] = fmaf(a0[i], b0[j], acc[i][j]);
    }
    __syncthreads();
  }
  #pragma unroll
  for (int i = 0; i < 4; ++i) {
    int row = bm + ty * 4 + i;
    if (row >= M) continue;
    #pragma unroll
    for (int j = 0; j < 4; ++j) {
      int col = bn + tx * 4 + j;
      if (col >= N) continue;
      float v = acc[i][j];
      if (bias) v += bias[col];
      if (ACT == 1) v = fmaxf(v, 0.0f) + log1pf(expf(-fabsf(v)));
      Cm[(size_t)row * N + col] = v;
    }
  }
}

// ---------------- xproj split-K partials ----------------
__global__ __launch_bounds__(256) void xproj_kernel(const float* __restrict__ xc,
    const float* __restrict__ w, float* __restrict__ part) {
  __shared__ float at[64][44];
  __shared__ float wt[32][80];
  int kc = blockIdx.x, mt = blockIdx.y;
  int t = threadIdx.x;
  int tx = t & 15, ty = t >> 4;
  float acc[4][5] = {};
  int sr = t >> 3, sc4 = (t & 7) * 4;
  for (int k0 = kc * 192; k0 < kc * 192 + 192; k0 += 32) {
    __syncthreads();
    float4 v0 = *reinterpret_cast<const float4*>(xc + (size_t)(mt * 64 + sr) * NIN + k0 + sc4);
    float4 v1 = *reinterpret_cast<const float4*>(xc + (size_t)(mt * 64 + sr + 32) * NIN + k0 + sc4);
    *reinterpret_cast<float4*>(&at[sr][sc4])      = v0;
    *reinterpret_cast<float4*>(&at[sr + 32][sc4]) = v1;
    for (int i = t; i < 32 * 80; i += 256)
      wt[i / 80][i % 80] = w[(size_t)(k0 + i / 80) * 80 + i % 80];
    __syncthreads();
    #pragma unroll
    for (int kk = 0; kk < 32; ++kk) {
      float a0[4], b0[5];
      #pragma unroll
      for (int i = 0; i < 4; ++i) a0[i] = at[ty * 4 + i][kk];
      #pragma unroll
      for (int j = 0; j < 5; ++j) b0[j] = wt[kk][tx + 16 * j];
      #pragma unroll
      for (int i = 0; i < 4; ++i)
        #pragma unroll
        for (int j = 0; j < 5; ++j)
          acc[i][j] = fmaf(a0[i], b0[j], acc[i][j]);
    }
  }
  #pragma unroll
  for (int i = 0; i < 4; ++i)
    #pragma unroll
    for (int j = 0; j < 5; ++j)
      part[((size_t)kc * Mn + mt * 64 + ty * 4 + i) * 80 + tx + 16 * j] = acc[i][j];
}

__global__ __launch_bounds__(256) void xpred_kernel(const float* __restrict__ part,
                                                    float* __restrict__ dbc) {
  int i = blockIdx.x * 256 + threadIdx.x;   // Mn*80 = 92160
  float s = 0.f;
  #pragma unroll
  for (int kc = 0; kc < 8; ++kc) s += part[(size_t)kc * (Mn * 80) + i];
  dbc[i] = s;
}

// ---------------- fused: split-K reduce + pe_b bias + LayerNorm -> interleaved h2 ----------------
__global__ __launch_bounds__(256) void ln_kernel(const float* __restrict__ part1,
    const float* __restrict__ peb, const float* __restrict__ g, const float* __restrict__ be,
    unsigned short* __restrict__ h2) {
  int row = blockIdx.x;
  int t = threadIdx.x;
  float vq[3];
  #pragma unroll
  for (int q = 0; q < 3; ++q) {
    int c = t + q * 256;
    float v = peb[c];
    #pragma unroll
    for (int ks = 0; ks < 8; ++ks)
      v += part1[((size_t)ks * Mn + row) * HID + c];
    vq[q] = v;
  }
  float s  = vq[0] + vq[1] + vq[2];
  float s2 = vq[0] * vq[0] + vq[1] * vq[1] + vq[2] * vq[2];
  #pragma unroll
  for (int o = 32; o > 0; o >>= 1) {
    s  += __shfl_down(s,  o, 64);
    s2 += __shfl_down(s2, o, 64);
  }
  __shared__ float red[8];
  int wid = t >> 6, lane = t & 63;
  if (lane == 0) { red[wid] = s; red[4 + wid] = s2; }
  __syncthreads();
  float S  = red[0] + red[1] + red[2] + red[3];
  float S2 = red[4] + red[5] + red[6] + red[7];
  float mu  = S * (1.0f / HID);
  float var = S2 * (1.0f / HID) - mu * mu;
  float inv = rsqrtf(var + 1e-5f);
  #pragma unroll
  for (int q = 0; q < 3; ++q) {
    int c = t + q * 256;
    float hv = (vq[q] - mu) * inv * g[c] + be[c];
    unsigned short hi, lo;
    split_bf(hv, hi, lo);
    size_t base = (size_t)row * (2 * HID) + col2(c);
    h2[base] = hi; h2[base + 32] = lo;
  }
}

// ---------------- depthwise conv (k=3) + silu ----------------
__global__ __launch_bounds__(256) void conv_silu_kernel(const float* __restrict__ xz,
    const float* __restrict__ w, const float* __restrict__ cb, float* __restrict__ xc) {
  int idx = blockIdx.x * 256 + threadIdx.x;
  if (idx >= Mn * NIN) return;
  int d  = idx % NIN;
  int bp = idx / NIN;
  int p = bp % Ln, b = bp / Ln;
  const float* base = xz + (size_t)(b * Ln) * (2 * NIN) + d;
  float acc = cb[d];
  float w0 = w[d * 3], w1 = w[d * 3 + 1], w2 = w[d * 3 + 2];
  if (p > 0)      acc += base[(size_t)(p - 1) * (2 * NIN)] * w0;
  acc += base[(size_t)p * (2 * NIN)] * w1;
  if (p < Ln - 1) acc += base[(size_t)(p + 1) * (2 * NIN)] * w2;
  float sg = 1.0f / (1.0f + expf(-acc));
  xc[idx] = acc * sg;
}

// ---------------- selective scan + D-residual + z-gate -> interleaved ya2 ----------------
__global__ __launch_bounds__(256) void scan_kernel(const float* __restrict__ delta,
    const float* __restrict__ dbc, const float* __restrict__ xcb,
    const float* __restrict__ A_log, const float* __restrict__ Dp,
    const float* __restrict__ xz, unsigned short* __restrict__ ya2) {
  __shared__ float Bsh[Ln][NST], Csh[Ln][NST];
  int b      = blockIdx.x / (NIN / 256);
  int dchunk = blockIdx.x % (NIN / 256);
  int t = threadIdx.x;
  if (t < Ln * NST) {
    int p = t / NST, n = t % NST;
    const float* row = dbc + (size_t)(b * Ln + p) * (DTR + 2 * NST);
    Bsh[p][n] = row[DTR + n];
    Csh[p][n] = row[DTR + NST + n];
  }
  __syncthreads();
  int d = dchunk * 256 + t;
  float Ar[NST];
  #pragma unroll
  for (int n = 0; n < NST; ++n) Ar[n] = -expf(A_log[(size_t)d * NST + n]);
  float s[NST];
  #pragma unroll
  for (int n = 0; n < NST; ++n) s[n] = 0.0f;
  float Dv = Dp[d];
  int cc = col2(d);
  for (int p = 0; p < Ln; ++p) {
    size_t off = (size_t)(b * Ln + p) * NIN + d;
    float dl = delta[off];
    float u  = xcb[off];
    float du = dl * u;
    float y = 0.0f;
    #pragma unroll
    for (int n = 0; n < NST; ++n) {
      float dA = expf(dl * Ar[n]);
      s[n] = dA * s[n] + du * Bsh[p][n];
      y += s[n] * Csh[p][n];
    }
    float zv = xz[(size_t)(b * Ln + p) * (2 * NIN) + NIN + d];
    float sz = zv / (1.0f + expf(-zv));
    float yv = (y + u * Dv) * sz;
    unsigned short hi, lo;
    split_bf(yv, hi, lo);
    size_t base = (size_t)(b * Ln + p) * (2 * NIN) + cc;
    ya2[base] = hi; ya2[base + 32] = lo;
  }
}

// ---------------- transpose + bilinear resize (3,3) -> (24,12) ----------------
__global__ __launch_bounds__(256) void resize_kernel(const float* __restrict__ o9,
                                                     float* __restrict__ out) {
  int idx = blockIdx.x * 256 + threadIdx.x;
  if (idx >= Bn * Cn * Hn) return;
  int y  = idx % Hn;
  int bc = idx / Hn;
  int c = bc % Cn, b = bc / Cn;
  float v[9];
  #pragma unroll
  for (int p = 0; p < 9; ++p) v[p] = o9[(size_t)(b * Ln + p) * Cn + c];
  float fy  = (y + 0.5f) * 0.125f - 0.5f;
  float fyf = floorf(fy);
  float wy  = fy - fyf;
  int y0 = (int)fyf, y1 = y0 + 1;
  y0 = min(2, max(0, y0)); y1 = min(2, max(0, y1));
  float rr[3];
  #pragma unroll
  for (int j = 0; j < 3; ++j) rr[j] = v[y0 * 3 + j] * (1.0f - wy) + v[y1 * 3 + j] * wy;
  float ov[12];
  #pragma unroll
  for (int xo = 0; xo < 12; ++xo) {
    float fx  = (xo + 0.5f) * 0.25f - 0.5f;
    float fxf = floorf(fx);
    float wx  = fx - fxf;
    int x0 = (int)fxf, x1 = x0 + 1;
    x0 = min(2, max(0, x0)); x1 = min(2, max(0, x1));
    ov[xo] = rr[x0] * (1.0f - wx) + rr[x1] * wx;
  }
  float4* op = reinterpret_cast<float4*>(out + (size_t)idx * 12);
  op[0] = make_float4(ov[0], ov[1], ov[2],  ov[3]);
  op[1] = make_float4(ov[4], ov[5], ov[6],  ov[7]);
  op[2] = make_float4(ov[8], ov[9], ov[10], ov[11]);
}

extern "C" void kernel_launch(void* const* d_in, const int* in_sizes, int n_in,
                              void* d_out, int out_size, void* d_ws, size_t ws_size,
                              hipStream_t stream) {
  const float* x        = (const float*)d_in[0];
  const float* pe_w     = (const float*)d_in[1];
  const float* pe_b     = (const float*)d_in[2];
  const float* ln_g     = (const float*)d_in[3];
  const float* ln_b     = (const float*)d_in[4];
  const float* in_w     = (const float*)d_in[5];
  const float* conv_w   = (const float*)d_in[6];
  const float* conv_b   = (const float*)d_in[7];
  const float* A_log    = (const float*)d_in[8];
  const float* xproj_w  = (const float*)d_in[9];
  const float* dtproj_w = (const float*)d_in[10];
  const float* dtproj_b = (const float*)d_in[11];
  const float* D_param  = (const float*)d_in[12];
  const float* out_w    = (const float*)d_in[13];
  float* out = (float*)d_out;
  char* ws = (char*)d_ws;

  size_t o = 0;
  auto alloc = [&](size_t bytes) { size_t r = o; o += (bytes + 255) & ~(size_t)255; return r; };
  unsigned short* tok2  = (unsigned short*)(ws + alloc((size_t)Mn * 2 * Cn * 2));
  unsigned short* peT2  = (unsigned short*)(ws + alloc((size_t)HID * 2 * Cn * 2));
  unsigned short* inT2  = (unsigned short*)(ws + alloc((size_t)2 * NIN * 2 * HID * 2));
  unsigned short* outT2 = (unsigned short*)(ws + alloc((size_t)Cn * 2 * NIN * 2));
  unsigned short* h2    = (unsigned short*)(ws + alloc((size_t)Mn * 2 * HID * 2));
  unsigned short* ya2   = (unsigned short*)(ws + alloc((size_t)Mn * 2 * NIN * 2));
  float* xz    = (float*)(ws + alloc((size_t)Mn * 2 * NIN * 4));
  float* xc    = (float*)(ws + alloc((size_t)Mn * NIN * 4));
  float* dbc   = (float*)(ws + alloc((size_t)Mn * 80 * 4));
  float* delta = (float*)(ws + alloc((size_t)Mn * NIN * 4));
  float* o9    = (float*)(ws + alloc((size_t)Mn * Cn * 4));
  float* part1 = (float*)(ws + alloc((size_t)8 * Mn * HID * 4));
  float* part2 = (float*)(ws + alloc((size_t)2 * Mn * 2 * NIN * 4));
  float* part3 = (float*)(ws + alloc((size_t)4 * Mn * Cn * 4));
  float* partx = (float*)(ws + alloc((size_t)8 * Mn * 80 * 4));

  // weight conversions (independent of activations)
  tconv_kernel<<<dim3(HID / 32, Cn / 32), 256, 0, stream>>>(pe_w, Cn, HID, peT2);
  tconv_kernel<<<dim3(2 * NIN / 32, HID / 32), 256, 0, stream>>>(in_w, HID, 2 * NIN, inT2);
  tconv_kernel<<<dim3(Cn / 32, NIN / 32), 256, 0, stream>>>(out_w, NIN, Cn, outT2);

  pool_kernel<<<Bn * (Cn / 32), 256, 0, stream>>>(x, tok2);
  // tok @ pe_w : M=1152 N=768 K=2048, split-K=8 -> grid 432
  mgemm_kernel<<<dim3(HID / 128, Mn / 128, 8), 256, 0, stream>>>(
      tok2, peT2, part1, Mn, HID, Cn, Cn / 8);
  ln_kernel<<<Mn, 256, 0, stream>>>(part1, pe_b, ln_g, ln_b, h2);
  // h @ in_w : M=1152 N=3072 K=768, split-K=2 -> grid 432
  mgemm_kernel<<<dim3(2 * NIN / 128, Mn / 128, 2), 256, 0, stream>>>(
      h2, inT2, part2, Mn, 2 * NIN, HID, HID / 2);
  red_kernel<2><<<(Mn * 2 * NIN) / 256, 256, 0, stream>>>(part2, xz, Mn * 2 * NIN);
  conv_silu_kernel<<<(Mn * NIN) / 256, 256, 0, stream>>>(xz, conv_w, conv_b, xc);
  xproj_kernel<<<dim3(8, Mn / 64), 256, 0, stream>>>(xc, xproj_w, partx);
  xpred_kernel<<<(Mn * 80) / 256, 256, 0, stream>>>(partx, dbc);
  gemm_kernel<1><<<dim3(NIN / 64, Mn / 64), 256, 0, stream>>>(
      dbc, 80, dtproj_w, dtproj_b, delta, Mn, NIN, DTR);
  scan_kernel<<<Bn * (NIN / 256), 256, 0, stream>>>(
      delta, dbc, xc, A_log, D_param, xz, ya2);
  // ya @ out_w : M=1152 N=2048 K=1536, split-K=4 -> grid 576
  mgemm_kernel<<<dim3(Cn / 128, Mn / 128, 4), 256, 0, stream>>>(
      ya2, outT2, part3, Mn, Cn, NIN, NIN / 4);
  red_kernel<4><<<(Mn * Cn) / 256, 256, 0, stream>>>(part3, o9, Mn * Cn);
  resize_kernel<<<(Bn * Cn * Hn) / 256, 256, 0, stream>>>(o9, out);
}

// Round 6
// 324.598 us; speedup vs baseline: 2.0374x; 1.1218x over previous
//
#include <hip/hip_runtime.h>
#include <math.h>

#define Bn   128
#define Cn   2048
#define Hn   24
#define Wn   12
#define HID  768
#define NIN  1536
#define NST  16
#define DTR  48
#define Ln   9
#define Mn   (Bn*Ln)   // 1152

typedef __bf16 bf16x8 __attribute__((ext_vector_type(8)));
typedef float  f32x4  __attribute__((ext_vector_type(4)));

// async global->LDS, 16B per lane; LDS dest is wave-uniform base + lane*16
#define GLOAD16(gsrc, ldst) \
  __builtin_amdgcn_global_load_lds((const __attribute__((address_space(1))) void*)(gsrc), \
                                   (__attribute__((address_space(3))) void*)(ldst), 16, 0, 0)

__device__ __forceinline__ unsigned short f2bf(float f) {
  unsigned u = __float_as_uint(f);
  u += 0x7fffu + ((u >> 16) & 1u);           // round-to-nearest-even
  return (unsigned short)(u >> 16);
}
__device__ __forceinline__ float bf2f(unsigned short h) {
  return __uint_as_float(((unsigned)h) << 16);
}
__device__ __forceinline__ void split_bf(float f, unsigned short& hi, unsigned short& lo) {
  hi = f2bf(f);
  lo = f2bf(f - bf2f(hi));
}
// interleaved hi/lo column index: per 32-k block, [hi 0..31 | lo 0..31]
__device__ __forceinline__ int col2(int k) { return ((k >> 5) << 6) + (k & 31); }

// ---------------- pooling: coalesced read via LDS (padded banks); 32 channels/block ------
__global__ __launch_bounds__(256) void pool_kernel(const float* __restrict__ x,
    unsigned short* __restrict__ tok2) {
  __shared__ float4 raw[32][73];                      // pad: bank stride 4 across channels
  int blk = blockIdx.x;                               // Bn * (Cn/32) = 8192
  int b = blk >> 6, cg = blk & 63;
  const float4* src = reinterpret_cast<const float4*>(x) + (size_t)(b * Cn + cg * 32) * 72;
  int t = threadIdx.x;
  #pragma unroll
  for (int it = 0; it < 9; ++it) {
    int li = it * 256 + t;
    raw[li / 72][li % 72] = src[li];
  }
  __syncthreads();
  for (int cell = t; cell < 288; cell += 256) {
    int c = cell / 9, p = cell % 9, i = p / 3, j = p % 3;
    float s = 0.f;
    #pragma unroll
    for (int k = 0; k < 8; ++k) {
      float4 v = raw[c][(i * 8 + k) * 3 + j];
      s += (v.x + v.y) + (v.z + v.w);
    }
    s *= (1.0f / 32.0f);
    unsigned short hi, lo;
    split_bf(s, hi, lo);
    int cglob = cg * 32 + c;
    size_t base = ((size_t)(b * Ln + p)) * (2 * Cn) + col2(cglob);
    tok2[base] = hi; tok2[base + 32] = lo;
  }
}

// ---------------- all 3 weight transposes in one launch ----------------
__global__ __launch_bounds__(256) void tconv_all_kernel(const float* __restrict__ pe_w,
    const float* __restrict__ in_w, const float* __restrict__ out_w,
    unsigned short* __restrict__ peT2, unsigned short* __restrict__ inT2,
    unsigned short* __restrict__ outT2) {
  __shared__ float tile[32][33];
  int bid = blockIdx.x;
  const float* W; unsigned short* T2; int K, N, nb, kb;
  if (bid < 1536)      { W = pe_w;  T2 = peT2;  K = Cn;  N = HID;     nb = bid % 24; kb = bid / 24; }
  else if (bid < 3840) { int q = bid - 1536; W = in_w;  T2 = inT2;  K = HID; N = 2 * NIN; nb = q % 96; kb = q / 96; }
  else                 { int q = bid - 3840; W = out_w; T2 = outT2; K = NIN; N = Cn;      nb = q % 64; kb = q / 64; }
  int t = threadIdx.x;
  int kl = t >> 3, n4 = (t & 7) * 4;
  float4 v = *reinterpret_cast<const float4*>(W + (size_t)(kb * 32 + kl) * N + nb * 32 + n4);
  tile[kl][n4] = v.x; tile[kl][n4 + 1] = v.y; tile[kl][n4 + 2] = v.z; tile[kl][n4 + 3] = v.w;
  __syncthreads();
  int nl = t >> 3, k4 = (t & 7) * 4;
  unsigned short hi[4], lo[4];
  #pragma unroll
  for (int i = 0; i < 4; ++i) split_bf(tile[k4 + i][nl], hi[i], lo[i]);
  size_t base = (size_t)(nb * 32 + nl) * (2 * K) + kb * 64 + k4;
  uint2 ph, pl;
  ph.x = (unsigned)hi[0] | ((unsigned)hi[1] << 16);
  ph.y = (unsigned)hi[2] | ((unsigned)hi[3] << 16);
  pl.x = (unsigned)lo[0] | ((unsigned)lo[1] << 16);
  pl.y = (unsigned)lo[2] | ((unsigned)lo[3] << 16);
  *reinterpret_cast<uint2*>(T2 + base)      = ph;
  *reinterpret_cast<uint2*>(T2 + base + 32) = pl;
}

// ------------- split-bf16 MFMA GEMM, global_load_lds staging with pre-swizzled source ----
__global__ __launch_bounds__(256) void mgemm_kernel(
    const unsigned short* __restrict__ A2, const unsigned short* __restrict__ B2,
    float* __restrict__ Cout, int M, int N, int K, int Ksub) {
  __shared__ unsigned short As[128][64];
  __shared__ unsigned short Bs[128][64];
  int t = threadIdx.x;
  int bm = blockIdx.y * 128, bn = blockIdx.x * 128;
  int wave = t >> 6, lane = t & 63;
  int wr = (wave >> 1) * 64, wc = (wave & 1) * 64;
  int lr = lane & 15, lk = lane >> 4;

  int l3 = lane >> 3, c8 = lane & 7;
  int sc = c8 ^ l3;
  size_t koff = (size_t)blockIdx.z * 2 * (size_t)Ksub;
  const unsigned short* Ab = A2 + (size_t)(bm + wave * 32 + l3) * (2 * (size_t)K) + koff + sc * 8;
  const unsigned short* Bb = B2 + (size_t)(bn + wave * 32 + l3) * (2 * (size_t)K) + koff + sc * 8;
  size_t rstep = (size_t)8 * 2 * K;
  unsigned short* AsW = &As[wave * 32][0];
  unsigned short* BsW = &Bs[wave * 32][0];

  f32x4 acc[4][4];
  #pragma unroll
  for (int m = 0; m < 4; ++m)
    #pragma unroll
    for (int n = 0; n < 4; ++n) acc[m][n] = {0.f, 0.f, 0.f, 0.f};

  for (int kk = 0; kk < Ksub; kk += 32) {
    __syncthreads();
    #pragma unroll
    for (int q = 0; q < 4; ++q) {
      GLOAD16(Ab + q * rstep + kk * 2, AsW + q * 8 * 64);
      GLOAD16(Bb + q * rstep + kk * 2, BsW + q * 8 * 64);
    }
    __syncthreads();

    bf16x8 ah[4], al[4], bh[4], bl[4];
    #pragma unroll
    for (int m = 0; m < 4; ++m) {
      int ar = wr + m * 16 + lr;
      ah[m] = *reinterpret_cast<const bf16x8*>(&As[ar][((lk    ) ^ (ar & 7)) * 8]);
      al[m] = *reinterpret_cast<const bf16x8*>(&As[ar][((4 + lk) ^ (ar & 7)) * 8]);
    }
    #pragma unroll
    for (int n = 0; n < 4; ++n) {
      int br = wc + n * 16 + lr;
      bh[n] = *reinterpret_cast<const bf16x8*>(&Bs[br][((lk    ) ^ (br & 7)) * 8]);
      bl[n] = *reinterpret_cast<const bf16x8*>(&Bs[br][((4 + lk) ^ (br & 7)) * 8]);
    }
    #pragma unroll
    for (int m = 0; m < 4; ++m)
      #pragma unroll
      for (int n = 0; n < 4; ++n) {
        acc[m][n] = __builtin_amdgcn_mfma_f32_16x16x32_bf16(ah[m], bh[n], acc[m][n], 0, 0, 0);
        acc[m][n] = __builtin_amdgcn_mfma_f32_16x16x32_bf16(ah[m], bl[n], acc[m][n], 0, 0, 0);
        acc[m][n] = __builtin_amdgcn_mfma_f32_16x16x32_bf16(al[m], bh[n], acc[m][n], 0, 0, 0);
      }
  }

  float* dst = Cout + (size_t)blockIdx.z * M * N;
  #pragma unroll
  for (int m = 0; m < 4; ++m)
    #pragma unroll
    for (int n = 0; n < 4; ++n) {
      int col = bn + wc + n * 16 + lr;
      #pragma unroll
      for (int r = 0; r < 4; ++r) {
        int row = bm + wr + m * 16 + lk * 4 + r;
        dst[(size_t)row * N + col] = acc[m][n][r];
      }
    }
}

// ---------------- xproj split-K partials (fp32) ----------------
__global__ __launch_bounds__(256) void xproj_kernel(const float* __restrict__ xc,
    const float* __restrict__ w, float* __restrict__ part) {
  __shared__ float at[64][44];
  __shared__ float wt[32][80];
  int kc = blockIdx.x, mt = blockIdx.y;
  int t = threadIdx.x;
  int tx = t & 15, ty = t >> 4;
  float acc[4][5] = {};
  int sr = t >> 3, sc4 = (t & 7) * 4;
  for (int k0 = kc * 192; k0 < kc * 192 + 192; k0 += 32) {
    __syncthreads();
    float4 v0 = *reinterpret_cast<const float4*>(xc + (size_t)(mt * 64 + sr) * NIN + k0 + sc4);
    float4 v1 = *reinterpret_cast<const float4*>(xc + (size_t)(mt * 64 + sr + 32) * NIN + k0 + sc4);
    *reinterpret_cast<float4*>(&at[sr][sc4])      = v0;
    *reinterpret_cast<float4*>(&at[sr + 32][sc4]) = v1;
    for (int i = t; i < 32 * 80; i += 256)
      wt[i / 80][i % 80] = w[(size_t)(k0 + i / 80) * 80 + i % 80];
    __syncthreads();
    #pragma unroll
    for (int kk = 0; kk < 32; ++kk) {
      float a0[4], b0[5];
      #pragma unroll
      for (int i = 0; i < 4; ++i) a0[i] = at[ty * 4 + i][kk];
      #pragma unroll
      for (int j = 0; j < 5; ++j) b0[j] = wt[kk][tx + 16 * j];
      #pragma unroll
      for (int i = 0; i < 4; ++i)
        #pragma unroll
        for (int j = 0; j < 5; ++j)
          acc[i][j] = fmaf(a0[i], b0[j], acc[i][j]);
    }
  }
  #pragma unroll
  for (int i = 0; i < 4; ++i)
    #pragma unroll
    for (int j = 0; j < 5; ++j)
      part[((size_t)kc * Mn + mt * 64 + ty * 4 + i) * 80 + tx + 16 * j] = acc[i][j];
}

__global__ __launch_bounds__(256) void xpred_kernel(const float* __restrict__ part,
                                                    float* __restrict__ dbc) {
  int i = blockIdx.x * 256 + threadIdx.x;   // Mn*80 = 92160
  float s = 0.f;
  #pragma unroll
  for (int kc = 0; kc < 8; ++kc) s += part[(size_t)kc * (Mn * 80) + i];
  dbc[i] = s;
}

// ---------------- fused: split-K reduce + pe_b bias + LayerNorm -> interleaved h2 --------
__global__ __launch_bounds__(256) void ln_kernel(const float* __restrict__ part1,
    const float* __restrict__ peb, const float* __restrict__ g, const float* __restrict__ be,
    unsigned short* __restrict__ h2) {
  int row = blockIdx.x;
  int t = threadIdx.x;
  float vq[3];
  #pragma unroll
  for (int q = 0; q < 3; ++q) {
    int c = t + q * 256;
    float v = peb[c];
    #pragma unroll
    for (int ks = 0; ks < 8; ++ks)
      v += part1[((size_t)ks * Mn + row) * HID + c];
    vq[q] = v;
  }
  float s  = vq[0] + vq[1] + vq[2];
  float s2 = vq[0] * vq[0] + vq[1] * vq[1] + vq[2] * vq[2];
  #pragma unroll
  for (int o = 32; o > 0; o >>= 1) {
    s  += __shfl_down(s,  o, 64);
    s2 += __shfl_down(s2, o, 64);
  }
  __shared__ float red[8];
  int wid = t >> 6, lane = t & 63;
  if (lane == 0) { red[wid] = s; red[4 + wid] = s2; }
  __syncthreads();
  float S  = red[0] + red[1] + red[2] + red[3];
  float S2 = red[4] + red[5] + red[6] + red[7];
  float mu  = S * (1.0f / HID);
  float var = S2 * (1.0f / HID) - mu * mu;
  float inv = rsqrtf(var + 1e-5f);
  #pragma unroll
  for (int q = 0; q < 3; ++q) {
    int c = t + q * 256;
    float hv = (vq[q] - mu) * inv * g[c] + be[c];
    unsigned short hi, lo;
    split_bf(hv, hi, lo);
    size_t base = (size_t)row * (2 * HID) + col2(c);
    h2[base] = hi; h2[base + 32] = lo;
  }
}

// ---------------- depthwise conv (k=3) + silu; reads part2 slices directly ----------------
__global__ __launch_bounds__(256) void conv_silu_kernel(const float* __restrict__ part2,
    const float* __restrict__ w, const float* __restrict__ cb, float* __restrict__ xc) {
  int idx = blockIdx.x * 256 + threadIdx.x;
  if (idx >= Mn * NIN) return;
  int d  = idx % NIN;
  int bp = idx / NIN;
  int p = bp % Ln, b = bp / Ln;
  const float* pa = part2 + (size_t)(b * Ln) * (2 * NIN) + d;
  const float* pb = pa + (size_t)Mn * 2 * NIN;
  float acc = cb[d];
  float w0 = w[d * 3], w1 = w[d * 3 + 1], w2 = w[d * 3 + 2];
  if (p > 0) {
    size_t o1 = (size_t)(p - 1) * (2 * NIN);
    acc += (pa[o1] + pb[o1]) * w0;
  }
  size_t o2 = (size_t)p * (2 * NIN);
  acc += (pa[o2] + pb[o2]) * w1;
  if (p < Ln - 1) {
    size_t o3 = (size_t)(p + 1) * (2 * NIN);
    acc += (pa[o3] + pb[o3]) * w2;
  }
  float sg = 1.0f / (1.0f + expf(-acc));
  xc[idx] = acc * sg;
}

// -------- fused scan: dt-proj (K=48) + softplus + selective scan + D-res + z-gate --------
__global__ __launch_bounds__(256) void scan_kernel(const float* __restrict__ dbc,
    const float* __restrict__ xcb, const float* __restrict__ A_log,
    const float* __restrict__ Dp, const float* __restrict__ part2,
    const float* __restrict__ dtw, const float* __restrict__ dtb,
    unsigned short* __restrict__ ya2) {
  __shared__ float wdt[DTR * 256];                    // [k][256 d] : 48 KB
  __shared__ float dbc9[Ln][DTR];
  __shared__ float Bsh[Ln][NST], Csh[Ln][NST];
  int b      = blockIdx.x / (NIN / 256);
  int dchunk = blockIdx.x % (NIN / 256);
  int t = threadIdx.x;
  // dt weight tile: wdt[k*256 + d] = dtw[k][dchunk*256+d]
  float4* w4 = reinterpret_cast<float4*>(wdt);
  #pragma unroll
  for (int it = 0; it < 12; ++it) {
    int i4 = it * 256 + t;                            // 0..3071 ; k = i4/64, c4 = i4%64
    int k = i4 >> 6, c4 = i4 & 63;
    w4[i4] = *reinterpret_cast<const float4*>(dtw + (size_t)k * NIN + dchunk * 256 + c4 * 4);
  }
  for (int i = t; i < Ln * DTR; i += 256) {
    int p = i / DTR, k = i - p * DTR;
    dbc9[p][k] = dbc[(size_t)(b * Ln + p) * 80 + k];
  }
  if (t < Ln * NST) {
    int p = t / NST, n = t % NST;
    const float* row = dbc + (size_t)(b * Ln + p) * 80;
    Bsh[p][n] = row[DTR + n];
    Csh[p][n] = row[DTR + NST + n];
  }
  __syncthreads();
  int d = dchunk * 256 + t;
  float Ar[NST];
  #pragma unroll
  for (int n = 0; n < NST; ++n) Ar[n] = -expf(A_log[(size_t)d * NST + n]);
  float s[NST];
  #pragma unroll
  for (int n = 0; n < NST; ++n) s[n] = 0.0f;
  float Dv = Dp[d];
  float bt = dtb[d];
  int cc = col2(d);
  const float* z0 = part2 + NIN + d;
  const float* z1 = z0 + (size_t)Mn * 2 * NIN;
  for (int p = 0; p < Ln; ++p) {
    size_t off = (size_t)(b * Ln + p) * NIN + d;
    // delta = softplus(dbc[:, :48] @ dtproj_w + b)
    float a = bt;
    #pragma unroll
    for (int k = 0; k < DTR; ++k) a = fmaf(dbc9[p][k], wdt[k * 256 + t], a);
    float dl = fmaxf(a, 0.0f) + log1pf(expf(-fabsf(a)));
    float u  = xcb[off];
    float du = dl * u;
    float y = 0.0f;
    #pragma unroll
    for (int n = 0; n < NST; ++n) {
      float dA = expf(dl * Ar[n]);
      s[n] = dA * s[n] + du * Bsh[p][n];
      y += s[n] * Csh[p][n];
    }
    size_t zoff = (size_t)(b * Ln + p) * (2 * NIN);
    float zv = z0[zoff] + z1[zoff];
    float sz = zv / (1.0f + expf(-zv));
    float yv = (y + u * Dv) * sz;
    unsigned short hi, lo;
    split_bf(yv, hi, lo);
    size_t base = (size_t)(b * Ln + p) * (2 * NIN) + cc;
    ya2[base] = hi; ya2[base + 32] = lo;
  }
}

// -------- fused: split-K reduce + transpose + bilinear resize, coalesced writes --------
__global__ __launch_bounds__(256) void resize_kernel(const float* __restrict__ part3,
                                                     float* __restrict__ out) {
  __shared__ float v[32][10];
  int blk = blockIdx.x;                               // Bn * (Cn/32) = 8192
  int b = blk >> 6, cg = blk & 63;
  int t = threadIdx.x;
  size_t MN3 = (size_t)Mn * Cn;
  for (int i = t; i < 288; i += 256) {
    int p = i >> 5, c = i & 31;
    size_t base = (size_t)(b * Ln + p) * Cn + cg * 32 + c;
    v[c][p] = part3[base] + part3[base + MN3] + part3[base + 2 * MN3] + part3[base + 3 * MN3];
  }
  __syncthreads();
  int ch = t >> 3, sub = t & 7;
  float* dst = out + ((size_t)b * Cn + cg * 32 + ch) * 288;
  #pragma unroll
  for (int q = 0; q < 9; ++q) {
    int f = sub + q * 8;                              // float4 index 0..71
    int y = f / 3, xq = f - y * 3;
    float fy  = (y + 0.5f) * 0.125f - 0.5f;
    float fyf = floorf(fy);
    float wy  = fy - fyf;
    int yy = (int)fyf;
    int y0 = min(2, max(0, yy)), y1 = min(2, max(0, yy + 1));
    float rr[3];
    #pragma unroll
    for (int j = 0; j < 3; ++j)
      rr[j] = v[ch][y0 * 3 + j] * (1.0f - wy) + v[ch][y1 * 3 + j] * wy;
    float ov[4];
    #pragma unroll
    for (int xi = 0; xi < 4; ++xi) {
      int xo = xq * 4 + xi;
      float fx  = (xo + 0.5f) * 0.25f - 0.5f;
      float fxf = floorf(fx);
      float wx  = fx - fxf;
      int xx = (int)fxf;
      int x0 = min(2, max(0, xx)), x1 = min(2, max(0, xx + 1));
      ov[xi] = rr[x0] * (1.0f - wx) + rr[x1] * wx;
    }
    *reinterpret_cast<float4*>(dst + f * 4) = make_float4(ov[0], ov[1], ov[2], ov[3]);
  }
}

extern "C" void kernel_launch(void* const* d_in, const int* in_sizes, int n_in,
                              void* d_out, int out_size, void* d_ws, size_t ws_size,
                              hipStream_t stream) {
  const float* x        = (const float*)d_in[0];
  const float* pe_w     = (const float*)d_in[1];
  const float* pe_b     = (const float*)d_in[2];
  const float* ln_g     = (const float*)d_in[3];
  const float* ln_b     = (const float*)d_in[4];
  const float* in_w     = (const float*)d_in[5];
  const float* conv_w   = (const float*)d_in[6];
  const float* conv_b   = (const float*)d_in[7];
  const float* A_log    = (const float*)d_in[8];
  const float* xproj_w  = (const float*)d_in[9];
  const float* dtproj_w = (const float*)d_in[10];
  const float* dtproj_b = (const float*)d_in[11];
  const float* D_param  = (const float*)d_in[12];
  const float* out_w    = (const float*)d_in[13];
  float* out = (float*)d_out;
  char* ws = (char*)d_ws;

  size_t o = 0;
  auto alloc = [&](size_t bytes) { size_t r = o; o += (bytes + 255) & ~(size_t)255; return r; };
  unsigned short* tok2  = (unsigned short*)(ws + alloc((size_t)Mn * 2 * Cn * 2));
  unsigned short* peT2  = (unsigned short*)(ws + alloc((size_t)HID * 2 * Cn * 2));
  unsigned short* inT2  = (unsigned short*)(ws + alloc((size_t)2 * NIN * 2 * HID * 2));
  unsigned short* outT2 = (unsigned short*)(ws + alloc((size_t)Cn * 2 * NIN * 2));
  unsigned short* h2    = (unsigned short*)(ws + alloc((size_t)Mn * 2 * HID * 2));
  unsigned short* ya2   = (unsigned short*)(ws + alloc((size_t)Mn * 2 * NIN * 2));
  float* xc    = (float*)(ws + alloc((size_t)Mn * NIN * 4));
  float* dbc   = (float*)(ws + alloc((size_t)Mn * 80 * 4));
  float* part1 = (float*)(ws + alloc((size_t)8 * Mn * HID * 4));
  float* part2 = (float*)(ws + alloc((size_t)2 * Mn * 2 * NIN * 4));
  float* part3 = (float*)(ws + alloc((size_t)4 * Mn * Cn * 4));
  float* partx = (float*)(ws + alloc((size_t)8 * Mn * 80 * 4));

  // weights: 3 transposes in one launch (1536 + 2304 + 3072 = 6912 blocks)
  tconv_all_kernel<<<6912, 256, 0, stream>>>(pe_w, in_w, out_w, peT2, inT2, outT2);

  pool_kernel<<<Bn * (Cn / 32), 256, 0, stream>>>(x, tok2);
  // tok @ pe_w : M=1152 N=768 K=2048, split-K=8 -> grid 432
  mgemm_kernel<<<dim3(HID / 128, Mn / 128, 8), 256, 0, stream>>>(
      tok2, peT2, part1, Mn, HID, Cn, Cn / 8);
  ln_kernel<<<Mn, 256, 0, stream>>>(part1, pe_b, ln_g, ln_b, h2);
  // h @ in_w : M=1152 N=3072 K=768, split-K=2 -> grid 432
  mgemm_kernel<<<dim3(2 * NIN / 128, Mn / 128, 2), 256, 0, stream>>>(
      h2, inT2, part2, Mn, 2 * NIN, HID, HID / 2);
  conv_silu_kernel<<<(Mn * NIN) / 256, 256, 0, stream>>>(part2, conv_w, conv_b, xc);
  xproj_kernel<<<dim3(8, Mn / 64), 256, 0, stream>>>(xc, xproj_w, partx);
  xpred_kernel<<<(Mn * 80) / 256, 256, 0, stream>>>(partx, dbc);
  scan_kernel<<<Bn * (NIN / 256), 256, 0, stream>>>(
      dbc, xc, A_log, D_param, part2, dtproj_w, dtproj_b, ya2);
  // ya @ out_w : M=1152 N=2048 K=1536, split-K=4 -> grid 576
  mgemm_kernel<<<dim3(Cn / 128, Mn / 128, 4), 256, 0, stream>>>(
      ya2, outT2, part3, Mn, Cn, NIN, NIN / 4);
  resize_kernel<<<Bn * (Cn / 32), 256, 0, stream>>>(part3, out);
}

// Round 7
// 312.314 us; speedup vs baseline: 2.1175x; 1.0393x over previous
//
#include <hip/hip_runtime.h>
#include <math.h>

#define Bn   128
#define Cn   2048
#define Hn   24
#define Wn   12
#define HID  768
#define NIN  1536
#define NST  16
#define DTR  48
#define Ln   9
#define Mn   (Bn*Ln)   // 1152
#define XKS  16        // xproj split-K slices

typedef __bf16 bf16x8 __attribute__((ext_vector_type(8)));
typedef float  f32x4  __attribute__((ext_vector_type(4)));

// async global->LDS, 16B per lane; LDS dest is wave-uniform base + lane*16
#define GLOAD16(gsrc, ldst) \
  __builtin_amdgcn_global_load_lds((const __attribute__((address_space(1))) void*)(gsrc), \
                                   (__attribute__((address_space(3))) void*)(ldst), 16, 0, 0)

__device__ __forceinline__ unsigned short f2bf(float f) {
  unsigned u = __float_as_uint(f);
  u += 0x7fffu + ((u >> 16) & 1u);           // round-to-nearest-even
  return (unsigned short)(u >> 16);
}
__device__ __forceinline__ float bf2f(unsigned short h) {
  return __uint_as_float(((unsigned)h) << 16);
}
__device__ __forceinline__ void split_bf(float f, unsigned short& hi, unsigned short& lo) {
  hi = f2bf(f);
  lo = f2bf(f - bf2f(hi));
}
// interleaved hi/lo column index: per 32-k block, [hi 0..31 | lo 0..31]
__device__ __forceinline__ int col2(int k) { return ((k >> 5) << 6) + (k & 31); }

// ---------------- prep: 3 weight transposes + pooling, one launch ----------------
// blocks 0..6911: tconv (pe_w 1536, in_w 2304, out_w 3072); blocks 6912..15103: pool
__global__ __launch_bounds__(256) void prep_kernel(const float* __restrict__ pe_w,
    const float* __restrict__ in_w, const float* __restrict__ out_w,
    const float* __restrict__ x,
    unsigned short* __restrict__ peT2, unsigned short* __restrict__ inT2,
    unsigned short* __restrict__ outT2, unsigned short* __restrict__ tok2) {
  __shared__ char smem[32 * 73 * 16];                 // union: pool raw / tconv tile
  int bid = blockIdx.x;
  int t = threadIdx.x;
  if (bid < 6912) {
    float (*tile)[33] = reinterpret_cast<float (*)[33]>(smem);
    const float* W; unsigned short* T2; int K, N, nb, kb;
    if (bid < 1536)      { W = pe_w;  T2 = peT2;  K = Cn;  N = HID;     nb = bid % 24; kb = bid / 24; }
    else if (bid < 3840) { int q = bid - 1536; W = in_w;  T2 = inT2;  K = HID; N = 2 * NIN; nb = q % 96; kb = q / 96; }
    else                 { int q = bid - 3840; W = out_w; T2 = outT2; K = NIN; N = Cn;      nb = q % 64; kb = q / 64; }
    int kl = t >> 3, n4 = (t & 7) * 4;
    float4 v = *reinterpret_cast<const float4*>(W + (size_t)(kb * 32 + kl) * N + nb * 32 + n4);
    tile[kl][n4] = v.x; tile[kl][n4 + 1] = v.y; tile[kl][n4 + 2] = v.z; tile[kl][n4 + 3] = v.w;
    __syncthreads();
    int nl = t >> 3, k4 = (t & 7) * 4;
    unsigned short hi[4], lo[4];
    #pragma unroll
    for (int i = 0; i < 4; ++i) split_bf(tile[k4 + i][nl], hi[i], lo[i]);
    size_t base = (size_t)(nb * 32 + nl) * (2 * K) + kb * 64 + k4;
    uint2 ph, pl;
    ph.x = (unsigned)hi[0] | ((unsigned)hi[1] << 16);
    ph.y = (unsigned)hi[2] | ((unsigned)hi[3] << 16);
    pl.x = (unsigned)lo[0] | ((unsigned)lo[1] << 16);
    pl.y = (unsigned)lo[2] | ((unsigned)lo[3] << 16);
    *reinterpret_cast<uint2*>(T2 + base)      = ph;
    *reinterpret_cast<uint2*>(T2 + base + 32) = pl;
  } else {
    float4 (*raw)[73] = reinterpret_cast<float4 (*)[73]>(smem);
    int blk = bid - 6912;                             // Bn * (Cn/32) = 8192
    int b = blk >> 6, cg = blk & 63;
    const float4* src = reinterpret_cast<const float4*>(x) + (size_t)(b * Cn + cg * 32) * 72;
    #pragma unroll
    for (int it = 0; it < 9; ++it) {
      int li = it * 256 + t;
      raw[li / 72][li % 72] = src[li];
    }
    __syncthreads();
    for (int cell = t; cell < 288; cell += 256) {
      int c = cell / 9, p = cell % 9, i = p / 3, j = p % 3;
      float s = 0.f;
      #pragma unroll
      for (int k = 0; k < 8; ++k) {
        float4 v = raw[c][(i * 8 + k) * 3 + j];
        s += (v.x + v.y) + (v.z + v.w);
      }
      s *= (1.0f / 32.0f);
      unsigned short hi, lo;
      split_bf(s, hi, lo);
      int cglob = cg * 32 + c;
      size_t base = ((size_t)(b * Ln + p)) * (2 * Cn) + col2(cglob);
      tok2[base] = hi; tok2[base + 32] = lo;
    }
  }
}

// ------------- split-bf16 MFMA GEMM, double-buffered LDS (2-phase pipeline) -------------
// C = A(M,K)*B^T(N,K); 128x128 tile, BK=32, 4 waves of 64x64; blockIdx.z = split-K slice.
// LDS invariant: LDS[row][pc] = global[row][pc ^ (row&7)] (16B chunks); gload_lds with
// pre-swizzled global source. Stage(t+1) issued BEFORE ds_read/MFMA(t); the barrier's
// implicit vmcnt drain lands after the MFMA phase.
__global__ __launch_bounds__(256) void mgemm_kernel(
    const unsigned short* __restrict__ A2, const unsigned short* __restrict__ B2,
    float* __restrict__ Cout, int M, int N, int K, int Ksub) {
  __shared__ unsigned short As[2][128][64];
  __shared__ unsigned short Bs[2][128][64];
  int t = threadIdx.x;
  int bm = blockIdx.y * 128, bn = blockIdx.x * 128;
  int wave = t >> 6, lane = t & 63;
  int wr = (wave >> 1) * 64, wc = (wave & 1) * 64;
  int lr = lane & 15, lk = lane >> 4;

  int l3 = lane >> 3, c8 = lane & 7;
  int sc = c8 ^ l3;
  size_t koff = (size_t)blockIdx.z * 2 * (size_t)Ksub;
  const unsigned short* Ab = A2 + (size_t)(bm + wave * 32 + l3) * (2 * (size_t)K) + koff + sc * 8;
  const unsigned short* Bb = B2 + (size_t)(bn + wave * 32 + l3) * (2 * (size_t)K) + koff + sc * 8;
  size_t rstep = (size_t)8 * 2 * K;

  f32x4 acc[4][4];
  #pragma unroll
  for (int m = 0; m < 4; ++m)
    #pragma unroll
    for (int n = 0; n < 4; ++n) acc[m][n] = {0.f, 0.f, 0.f, 0.f};

  // prologue: stage k-step 0 into buffer 0
  {
    unsigned short* AsW = &As[0][wave * 32][0];
    unsigned short* BsW = &Bs[0][wave * 32][0];
    #pragma unroll
    for (int q = 0; q < 4; ++q) {
      GLOAD16(Ab + q * rstep, AsW + q * 8 * 64);
      GLOAD16(Bb + q * rstep, BsW + q * 8 * 64);
    }
  }
  __syncthreads();                                    // vmcnt(0) drain + barrier

  int cur = 0;
  for (int kk = 0; kk < Ksub; kk += 32) {
    if (kk + 32 < Ksub) {                             // issue next-tile stage first
      unsigned short* AsW = &As[cur ^ 1][wave * 32][0];
      unsigned short* BsW = &Bs[cur ^ 1][wave * 32][0];
      #pragma unroll
      for (int q = 0; q < 4; ++q) {
        GLOAD16(Ab + q * rstep + (kk + 32) * 2, AsW + q * 8 * 64);
        GLOAD16(Bb + q * rstep + (kk + 32) * 2, BsW + q * 8 * 64);
      }
    }

    bf16x8 ah[4], al[4], bh[4], bl[4];
    #pragma unroll
    for (int m = 0; m < 4; ++m) {
      int ar = wr + m * 16 + lr;
      ah[m] = *reinterpret_cast<const bf16x8*>(&As[cur][ar][((lk    ) ^ (ar & 7)) * 8]);
      al[m] = *reinterpret_cast<const bf16x8*>(&As[cur][ar][((4 + lk) ^ (ar & 7)) * 8]);
    }
    #pragma unroll
    for (int n = 0; n < 4; ++n) {
      int br = wc + n * 16 + lr;
      bh[n] = *reinterpret_cast<const bf16x8*>(&Bs[cur][br][((lk    ) ^ (br & 7)) * 8]);
      bl[n] = *reinterpret_cast<const bf16x8*>(&Bs[cur][br][((4 + lk) ^ (br & 7)) * 8]);
    }
    #pragma unroll
    for (int m = 0; m < 4; ++m)
      #pragma unroll
      for (int n = 0; n < 4; ++n) {
        acc[m][n] = __builtin_amdgcn_mfma_f32_16x16x32_bf16(ah[m], bh[n], acc[m][n], 0, 0, 0);
        acc[m][n] = __builtin_amdgcn_mfma_f32_16x16x32_bf16(ah[m], bl[n], acc[m][n], 0, 0, 0);
        acc[m][n] = __builtin_amdgcn_mfma_f32_16x16x32_bf16(al[m], bh[n], acc[m][n], 0, 0, 0);
      }
    __syncthreads();                                  // next buffer staged + cur reads done
    cur ^= 1;
  }

  float* dst = Cout + (size_t)blockIdx.z * M * N;
  #pragma unroll
  for (int m = 0; m < 4; ++m)
    #pragma unroll
    for (int n = 0; n < 4; ++n) {
      int col = bn + wc + n * 16 + lr;
      #pragma unroll
      for (int r = 0; r < 4; ++r) {
        int row = bm + wr + m * 16 + lk * 4 + r;
        dst[(size_t)row * N + col] = acc[m][n][r];
      }
    }
}

// ---------------- xproj split-K partials (fp32), XKS slices ----------------
__global__ __launch_bounds__(256) void xproj_kernel(const float* __restrict__ xc,
    const float* __restrict__ w, float* __restrict__ part) {
  __shared__ float at[64][44];
  __shared__ float wt[32][80];
  int kc = blockIdx.x, mt = blockIdx.y;
  int t = threadIdx.x;
  int tx = t & 15, ty = t >> 4;
  float acc[4][5] = {};
  int sr = t >> 3, sc4 = (t & 7) * 4;
  for (int k0 = kc * 96; k0 < kc * 96 + 96; k0 += 32) {
    __syncthreads();
    float4 v0 = *reinterpret_cast<const float4*>(xc + (size_t)(mt * 64 + sr) * NIN + k0 + sc4);
    float4 v1 = *reinterpret_cast<const float4*>(xc + (size_t)(mt * 64 + sr + 32) * NIN + k0 + sc4);
    *reinterpret_cast<float4*>(&at[sr][sc4])      = v0;
    *reinterpret_cast<float4*>(&at[sr + 32][sc4]) = v1;
    for (int i = t; i < 32 * 80; i += 256)
      wt[i / 80][i % 80] = w[(size_t)(k0 + i / 80) * 80 + i % 80];
    __syncthreads();
    #pragma unroll
    for (int kk = 0; kk < 32; ++kk) {
      float a0[4], b0[5];
      #pragma unroll
      for (int i = 0; i < 4; ++i) a0[i] = at[ty * 4 + i][kk];
      #pragma unroll
      for (int j = 0; j < 5; ++j) b0[j] = wt[kk][tx + 16 * j];
      #pragma unroll
      for (int i = 0; i < 4; ++i)
        #pragma unroll
        for (int j = 0; j < 5; ++j)
          acc[i][j] = fmaf(a0[i], b0[j], acc[i][j]);
    }
  }
  #pragma unroll
  for (int i = 0; i < 4; ++i)
    #pragma unroll
    for (int j = 0; j < 5; ++j)
      part[((size_t)kc * Mn + mt * 64 + ty * 4 + i) * 80 + tx + 16 * j] = acc[i][j];
}

// ---------------- fused: split-K reduce + pe_b bias + LayerNorm -> interleaved h2 --------
__global__ __launch_bounds__(256) void ln_kernel(const float* __restrict__ part1,
    const float* __restrict__ peb, const float* __restrict__ g, const float* __restrict__ be,
    unsigned short* __restrict__ h2) {
  int row = blockIdx.x;
  int t = threadIdx.x;
  float vq[3];
  #pragma unroll
  for (int q = 0; q < 3; ++q) {
    int c = t + q * 256;
    float v = peb[c];
    #pragma unroll
    for (int ks = 0; ks < 8; ++ks)
      v += part1[((size_t)ks * Mn + row) * HID + c];
    vq[q] = v;
  }
  float s  = vq[0] + vq[1] + vq[2];
  float s2 = vq[0] * vq[0] + vq[1] * vq[1] + vq[2] * vq[2];
  #pragma unroll
  for (int o = 32; o > 0; o >>= 1) {
    s  += __shfl_down(s,  o, 64);
    s2 += __shfl_down(s2, o, 64);
  }
  __shared__ float red[8];
  int wid = t >> 6, lane = t & 63;
  if (lane == 0) { red[wid] = s; red[4 + wid] = s2; }
  __syncthreads();
  float S  = red[0] + red[1] + red[2] + red[3];
  float S2 = red[4] + red[5] + red[6] + red[7];
  float mu  = S * (1.0f / HID);
  float var = S2 * (1.0f / HID) - mu * mu;
  float inv = rsqrtf(var + 1e-5f);
  #pragma unroll
  for (int q = 0; q < 3; ++q) {
    int c = t + q * 256;
    float hv = (vq[q] - mu) * inv * g[c] + be[c];
    unsigned short hi, lo;
    split_bf(hv, hi, lo);
    size_t base = (size_t)row * (2 * HID) + col2(c);
    h2[base] = hi; h2[base + 32] = lo;
  }
}

// ---------------- depthwise conv (k=3) + silu; reads part2 slices directly ----------------
__global__ __launch_bounds__(256) void conv_silu_kernel(const float* __restrict__ part2,
    const float* __restrict__ w, const float* __restrict__ cb, float* __restrict__ xc) {
  int idx = blockIdx.x * 256 + threadIdx.x;
  if (idx >= Mn * NIN) return;
  int d  = idx % NIN;
  int bp = idx / NIN;
  int p = bp % Ln, b = bp / Ln;
  const float* pa = part2 + (size_t)(b * Ln) * (2 * NIN) + d;
  const float* pb = pa + (size_t)Mn * 2 * NIN;
  float acc = cb[d];
  float w0 = w[d * 3], w1 = w[d * 3 + 1], w2 = w[d * 3 + 2];
  if (p > 0) {
    size_t o1 = (size_t)(p - 1) * (2 * NIN);
    acc += (pa[o1] + pb[o1]) * w0;
  }
  size_t o2 = (size_t)p * (2 * NIN);
  acc += (pa[o2] + pb[o2]) * w1;
  if (p < Ln - 1) {
    size_t o3 = (size_t)(p + 1) * (2 * NIN);
    acc += (pa[o3] + pb[o3]) * w2;
  }
  float sg = 1.0f / (1.0f + expf(-acc));
  xc[idx] = acc * sg;
}

// -- fused scan: xproj-partial reduce + dt-proj (K=48) + softplus + scan + D-res + z-gate --
__global__ __launch_bounds__(256) void scan_kernel(const float* __restrict__ partx,
    const float* __restrict__ xcb, const float* __restrict__ A_log,
    const float* __restrict__ Dp, const float* __restrict__ part2,
    const float* __restrict__ dtw, const float* __restrict__ dtb,
    unsigned short* __restrict__ ya2) {
  __shared__ float wdt[DTR * 256];                    // [k][256 d] : 48 KB
  __shared__ float dbc9[Ln][DTR];
  __shared__ float Bsh[Ln][NST], Csh[Ln][NST];
  int b      = blockIdx.x / (NIN / 256);
  int dchunk = blockIdx.x % (NIN / 256);
  int t = threadIdx.x;
  // dt weight tile: wdt[k*256 + d] = dtw[k][dchunk*256+d]
  float4* w4 = reinterpret_cast<float4*>(wdt);
  #pragma unroll
  for (int it = 0; it < 12; ++it) {
    int i4 = it * 256 + t;
    int k = i4 >> 6, c4 = i4 & 63;
    w4[i4] = *reinterpret_cast<const float4*>(dtw + (size_t)k * NIN + dchunk * 256 + c4 * 4);
  }
  // dbc = sum of XKS xproj partial slices (fused xpred)
  for (int i = t; i < Ln * 80; i += 256) {
    int p = i / 80, k = i - p * 80;
    size_t off = (size_t)(b * Ln + p) * 80 + k;
    float s = 0.f;
    #pragma unroll
    for (int ks = 0; ks < XKS; ++ks) s += partx[(size_t)ks * (Mn * 80) + off];
    if (k < DTR)            dbc9[p][k] = s;
    else if (k < DTR + NST) Bsh[p][k - DTR] = s;
    else                    Csh[p][k - DTR - NST] = s;
  }
  __syncthreads();
  int d = dchunk * 256 + t;
  float Ar[NST];
  #pragma unroll
  for (int n = 0; n < NST; ++n) Ar[n] = -expf(A_log[(size_t)d * NST + n]);
  float s[NST];
  #pragma unroll
  for (int n = 0; n < NST; ++n) s[n] = 0.0f;
  float Dv = Dp[d];
  float bt = dtb[d];
  int cc = col2(d);
  const float* z0 = part2 + NIN + d;
  const float* z1 = z0 + (size_t)Mn * 2 * NIN;
  for (int p = 0; p < Ln; ++p) {
    size_t off = (size_t)(b * Ln + p) * NIN + d;
    float a = bt;
    #pragma unroll
    for (int k = 0; k < DTR; ++k) a = fmaf(dbc9[p][k], wdt[k * 256 + t], a);
    float dl = fmaxf(a, 0.0f) + log1pf(expf(-fabsf(a)));
    float u  = xcb[off];
    float du = dl * u;
    float y = 0.0f;
    #pragma unroll
    for (int n = 0; n < NST; ++n) {
      float dA = expf(dl * Ar[n]);
      s[n] = dA * s[n] + du * Bsh[p][n];
      y += s[n] * Csh[p][n];
    }
    size_t zoff = (size_t)(b * Ln + p) * (2 * NIN);
    float zv = z0[zoff] + z1[zoff];
    float sz = zv / (1.0f + expf(-zv));
    float yv = (y + u * Dv) * sz;
    unsigned short hi, lo;
    split_bf(yv, hi, lo);
    size_t base = (size_t)(b * Ln + p) * (2 * NIN) + cc;
    ya2[base] = hi; ya2[base + 32] = lo;
  }
}

// -------- fused: split-K reduce + transpose + bilinear resize, coalesced writes --------
__global__ __launch_bounds__(256) void resize_kernel(const float* __restrict__ part3,
                                                     float* __restrict__ out) {
  __shared__ float v[32][10];
  int blk = blockIdx.x;                               // Bn * (Cn/32) = 8192
  int b = blk >> 6, cg = blk & 63;
  int t = threadIdx.x;
  size_t MN3 = (size_t)Mn * Cn;
  for (int i = t; i < 288; i += 256) {
    int p = i >> 5, c = i & 31;
    size_t base = (size_t)(b * Ln + p) * Cn + cg * 32 + c;
    v[c][p] = part3[base] + part3[base + MN3] + part3[base + 2 * MN3] + part3[base + 3 * MN3];
  }
  __syncthreads();
  int ch = t >> 3, sub = t & 7;
  float* dst = out + ((size_t)b * Cn + cg * 32 + ch) * 288;
  #pragma unroll
  for (int q = 0; q < 9; ++q) {
    int f = sub + q * 8;
    int y = f / 3, xq = f - y * 3;
    float fy  = (y + 0.5f) * 0.125f - 0.5f;
    float fyf = floorf(fy);
    float wy  = fy - fyf;
    int yy = (int)fyf;
    int y0 = min(2, max(0, yy)), y1 = min(2, max(0, yy + 1));
    float rr[3];
    #pragma unroll
    for (int j = 0; j < 3; ++j)
      rr[j] = v[ch][y0 * 3 + j] * (1.0f - wy) + v[ch][y1 * 3 + j] * wy;
    float ov[4];
    #pragma unroll
    for (int xi = 0; xi < 4; ++xi) {
      int xo = xq * 4 + xi;
      float fx  = (xo + 0.5f) * 0.25f - 0.5f;
      float fxf = floorf(fx);
      float wx  = fx - fxf;
      int xx = (int)fxf;
      int x0 = min(2, max(0, xx)), x1 = min(2, max(0, xx + 1));
      ov[xi] = rr[x0] * (1.0f - wx) + rr[x1] * wx;
    }
    *reinterpret_cast<float4*>(dst + f * 4) = make_float4(ov[0], ov[1], ov[2], ov[3]);
  }
}

extern "C" void kernel_launch(void* const* d_in, const int* in_sizes, int n_in,
                              void* d_out, int out_size, void* d_ws, size_t ws_size,
                              hipStream_t stream) {
  const float* x        = (const float*)d_in[0];
  const float* pe_w     = (const float*)d_in[1];
  const float* pe_b     = (const float*)d_in[2];
  const float* ln_g     = (const float*)d_in[3];
  const float* ln_b     = (const float*)d_in[4];
  const float* in_w     = (const float*)d_in[5];
  const float* conv_w   = (const float*)d_in[6];
  const float* conv_b   = (const float*)d_in[7];
  const float* A_log    = (const float*)d_in[8];
  const float* xproj_w  = (const float*)d_in[9];
  const float* dtproj_w = (const float*)d_in[10];
  const float* dtproj_b = (const float*)d_in[11];
  const float* D_param  = (const float*)d_in[12];
  const float* out_w    = (const float*)d_in[13];
  float* out = (float*)d_out;
  char* ws = (char*)d_ws;

  size_t o = 0;
  auto alloc = [&](size_t bytes) { size_t r = o; o += (bytes + 255) & ~(size_t)255; return r; };
  unsigned short* tok2  = (unsigned short*)(ws + alloc((size_t)Mn * 2 * Cn * 2));
  unsigned short* peT2  = (unsigned short*)(ws + alloc((size_t)HID * 2 * Cn * 2));
  unsigned short* inT2  = (unsigned short*)(ws + alloc((size_t)2 * NIN * 2 * HID * 2));
  unsigned short* outT2 = (unsigned short*)(ws + alloc((size_t)Cn * 2 * NIN * 2));
  unsigned short* h2    = (unsigned short*)(ws + alloc((size_t)Mn * 2 * HID * 2));
  unsigned short* ya2   = (unsigned short*)(ws + alloc((size_t)Mn * 2 * NIN * 2));
  float* xc    = (float*)(ws + alloc((size_t)Mn * NIN * 4));
  float* part1 = (float*)(ws + alloc((size_t)8 * Mn * HID * 4));
  float* part2 = (float*)(ws + alloc((size_t)2 * Mn * 2 * NIN * 4));
  float* part3 = (float*)(ws + alloc((size_t)4 * Mn * Cn * 4));
  float* partx = (float*)(ws + alloc((size_t)XKS * Mn * 80 * 4));

  // prep: weight transposes (6912 blocks) + pooling (8192 blocks)
  prep_kernel<<<15104, 256, 0, stream>>>(pe_w, in_w, out_w, x, peT2, inT2, outT2, tok2);

  // tok @ pe_w : M=1152 N=768 K=2048, split-K=8 -> grid 432
  mgemm_kernel<<<dim3(HID / 128, Mn / 128, 8), 256, 0, stream>>>(
      tok2, peT2, part1, Mn, HID, Cn, Cn / 8);
  ln_kernel<<<Mn, 256, 0, stream>>>(part1, pe_b, ln_g, ln_b, h2);
  // h @ in_w : M=1152 N=3072 K=768, split-K=2 -> grid 432
  mgemm_kernel<<<dim3(2 * NIN / 128, Mn / 128, 2), 256, 0, stream>>>(
      h2, inT2, part2, Mn, 2 * NIN, HID, HID / 2);
  conv_silu_kernel<<<(Mn * NIN) / 256, 256, 0, stream>>>(part2, conv_w, conv_b, xc);
  xproj_kernel<<<dim3(XKS, Mn / 64), 256, 0, stream>>>(xc, xproj_w, partx);
  scan_kernel<<<Bn * (NIN / 256), 256, 0, stream>>>(
      partx, xc, A_log, D_param, part2, dtproj_w, dtproj_b, ya2);
  // ya @ out_w : M=1152 N=2048 K=1536, split-K=4 -> grid 576
  mgemm_kernel<<<dim3(Cn / 128, Mn / 128, 4), 256, 0, stream>>>(
      ya2, outT2, part3, Mn, Cn, NIN, NIN / 4);
  resize_kernel<<<Bn * (Cn / 32), 256, 0, stream>>>(part3, out);
}

// Round 8
// 302.383 us; speedup vs baseline: 2.1871x; 1.0328x over previous
//
#include <hip/hip_runtime.h>
#include <math.h>

#define Bn   128
#define Cn   2048
#define Hn   24
#define Wn   12
#define HID  768
#define NIN  1536
#define NST  16
#define DTR  48
#define Ln   9
#define Mn   (Bn*Ln)   // 1152
#define XKS  16        // xproj split-K slices

typedef __bf16 bf16x8 __attribute__((ext_vector_type(8)));
typedef float  f32x4  __attribute__((ext_vector_type(4)));

// async global->LDS, 16B per lane; LDS dest is wave-uniform base + lane*16
#define GLOAD16(gsrc, ldst) \
  __builtin_amdgcn_global_load_lds((const __attribute__((address_space(1))) void*)(gsrc), \
                                   (__attribute__((address_space(3))) void*)(ldst), 16, 0, 0)

__device__ __forceinline__ unsigned short f2bf(float f) {
  unsigned u = __float_as_uint(f);
  u += 0x7fffu + ((u >> 16) & 1u);           // round-to-nearest-even
  return (unsigned short)(u >> 16);
}
__device__ __forceinline__ float bf2f(unsigned short h) {
  return __uint_as_float(((unsigned)h) << 16);
}
__device__ __forceinline__ void split_bf(float f, unsigned short& hi, unsigned short& lo) {
  hi = f2bf(f);
  lo = f2bf(f - bf2f(hi));
}
// interleaved hi/lo column index: per 32-k block, [hi 0..31 | lo 0..31]
__device__ __forceinline__ int col2(int k) { return ((k >> 5) << 6) + (k & 31); }

// ---------------- prep: 3 weight transposes + pooling, one launch ----------------
__global__ __launch_bounds__(256) void prep_kernel(const float* __restrict__ pe_w,
    const float* __restrict__ in_w, const float* __restrict__ out_w,
    const float* __restrict__ x,
    unsigned short* __restrict__ peT2, unsigned short* __restrict__ inT2,
    unsigned short* __restrict__ outT2, unsigned short* __restrict__ tok2) {
  __shared__ char smem[32 * 73 * 16];                 // union: pool raw / tconv tile
  int bid = blockIdx.x;
  int t = threadIdx.x;
  if (bid < 6912) {
    float (*tile)[33] = reinterpret_cast<float (*)[33]>(smem);
    const float* W; unsigned short* T2; int K, N, nb, kb;
    if (bid < 1536)      { W = pe_w;  T2 = peT2;  K = Cn;  N = HID;     nb = bid % 24; kb = bid / 24; }
    else if (bid < 3840) { int q = bid - 1536; W = in_w;  T2 = inT2;  K = HID; N = 2 * NIN; nb = q % 96; kb = q / 96; }
    else                 { int q = bid - 3840; W = out_w; T2 = outT2; K = NIN; N = Cn;      nb = q % 64; kb = q / 64; }
    int kl = t >> 3, n4 = (t & 7) * 4;
    float4 v = *reinterpret_cast<const float4*>(W + (size_t)(kb * 32 + kl) * N + nb * 32 + n4);
    tile[kl][n4] = v.x; tile[kl][n4 + 1] = v.y; tile[kl][n4 + 2] = v.z; tile[kl][n4 + 3] = v.w;
    __syncthreads();
    int nl = t >> 3, k4 = (t & 7) * 4;
    unsigned short hi[4], lo[4];
    #pragma unroll
    for (int i = 0; i < 4; ++i) split_bf(tile[k4 + i][nl], hi[i], lo[i]);
    size_t base = (size_t)(nb * 32 + nl) * (2 * K) + kb * 64 + k4;
    uint2 ph, pl;
    ph.x = (unsigned)hi[0] | ((unsigned)hi[1] << 16);
    ph.y = (unsigned)hi[2] | ((unsigned)hi[3] << 16);
    pl.x = (unsigned)lo[0] | ((unsigned)lo[1] << 16);
    pl.y = (unsigned)lo[2] | ((unsigned)lo[3] << 16);
    *reinterpret_cast<uint2*>(T2 + base)      = ph;
    *reinterpret_cast<uint2*>(T2 + base + 32) = pl;
  } else {
    float4 (*raw)[73] = reinterpret_cast<float4 (*)[73]>(smem);
    int blk = bid - 6912;                             // Bn * (Cn/32) = 8192
    int b = blk >> 6, cg = blk & 63;
    const float4* src = reinterpret_cast<const float4*>(x) + (size_t)(b * Cn + cg * 32) * 72;
    #pragma unroll
    for (int it = 0; it < 9; ++it) {
      int li = it * 256 + t;
      raw[li / 72][li % 72] = src[li];
    }
    __syncthreads();
    for (int cell = t; cell < 288; cell += 256) {
      int c = cell / 9, p = cell % 9, i = p / 3, j = p % 3;
      float s = 0.f;
      #pragma unroll
      for (int k = 0; k < 8; ++k) {
        float4 v = raw[c][(i * 8 + k) * 3 + j];
        s += (v.x + v.y) + (v.z + v.w);
      }
      s *= (1.0f / 32.0f);
      unsigned short hi, lo;
      split_bf(s, hi, lo);
      int cglob = cg * 32 + c;
      size_t base = ((size_t)(b * Ln + p)) * (2 * Cn) + col2(cglob);
      tok2[base] = hi; tok2[base + 32] = lo;
    }
  }
}

// ------------- split-bf16 MFMA GEMM, double-buffered LDS, gload_lds staging -------------
__global__ __launch_bounds__(256) void mgemm_kernel(
    const unsigned short* __restrict__ A2, const unsigned short* __restrict__ B2,
    float* __restrict__ Cout, int M, int N, int K, int Ksub) {
  __shared__ unsigned short As[2][128][64];
  __shared__ unsigned short Bs[2][128][64];
  int t = threadIdx.x;
  int bm = blockIdx.y * 128, bn = blockIdx.x * 128;
  int wave = t >> 6, lane = t & 63;
  int wr = (wave >> 1) * 64, wc = (wave & 1) * 64;
  int lr = lane & 15, lk = lane >> 4;

  int l3 = lane >> 3, c8 = lane & 7;
  int sc = c8 ^ l3;
  size_t koff = (size_t)blockIdx.z * 2 * (size_t)Ksub;
  const unsigned short* Ab = A2 + (size_t)(bm + wave * 32 + l3) * (2 * (size_t)K) + koff + sc * 8;
  const unsigned short* Bb = B2 + (size_t)(bn + wave * 32 + l3) * (2 * (size_t)K) + koff + sc * 8;
  size_t rstep = (size_t)8 * 2 * K;

  f32x4 acc[4][4];
  #pragma unroll
  for (int m = 0; m < 4; ++m)
    #pragma unroll
    for (int n = 0; n < 4; ++n) acc[m][n] = {0.f, 0.f, 0.f, 0.f};

  {
    unsigned short* AsW = &As[0][wave * 32][0];
    unsigned short* BsW = &Bs[0][wave * 32][0];
    #pragma unroll
    for (int q = 0; q < 4; ++q) {
      GLOAD16(Ab + q * rstep, AsW + q * 8 * 64);
      GLOAD16(Bb + q * rstep, BsW + q * 8 * 64);
    }
  }
  __syncthreads();

  int cur = 0;
  for (int kk = 0; kk < Ksub; kk += 32) {
    if (kk + 32 < Ksub) {
      unsigned short* AsW = &As[cur ^ 1][wave * 32][0];
      unsigned short* BsW = &Bs[cur ^ 1][wave * 32][0];
      #pragma unroll
      for (int q = 0; q < 4; ++q) {
        GLOAD16(Ab + q * rstep + (kk + 32) * 2, AsW + q * 8 * 64);
        GLOAD16(Bb + q * rstep + (kk + 32) * 2, BsW + q * 8 * 64);
      }
    }

    bf16x8 ah[4], al[4], bh[4], bl[4];
    #pragma unroll
    for (int m = 0; m < 4; ++m) {
      int ar = wr + m * 16 + lr;
      ah[m] = *reinterpret_cast<const bf16x8*>(&As[cur][ar][((lk    ) ^ (ar & 7)) * 8]);
      al[m] = *reinterpret_cast<const bf16x8*>(&As[cur][ar][((4 + lk) ^ (ar & 7)) * 8]);
    }
    #pragma unroll
    for (int n = 0; n < 4; ++n) {
      int br = wc + n * 16 + lr;
      bh[n] = *reinterpret_cast<const bf16x8*>(&Bs[cur][br][((lk    ) ^ (br & 7)) * 8]);
      bl[n] = *reinterpret_cast<const bf16x8*>(&Bs[cur][br][((4 + lk) ^ (br & 7)) * 8]);
    }
    #pragma unroll
    for (int m = 0; m < 4; ++m)
      #pragma unroll
      for (int n = 0; n < 4; ++n) {
        acc[m][n] = __builtin_amdgcn_mfma_f32_16x16x32_bf16(ah[m], bh[n], acc[m][n], 0, 0, 0);
        acc[m][n] = __builtin_amdgcn_mfma_f32_16x16x32_bf16(ah[m], bl[n], acc[m][n], 0, 0, 0);
        acc[m][n] = __builtin_amdgcn_mfma_f32_16x16x32_bf16(al[m], bh[n], acc[m][n], 0, 0, 0);
      }
    __syncthreads();
    cur ^= 1;
  }

  float* dst = Cout + (size_t)blockIdx.z * M * N;
  #pragma unroll
  for (int m = 0; m < 4; ++m)
    #pragma unroll
    for (int n = 0; n < 4; ++n) {
      int col = bn + wc + n * 16 + lr;
      #pragma unroll
      for (int r = 0; r < 4; ++r) {
        int row = bm + wr + m * 16 + lk * 4 + r;
        dst[(size_t)row * N + col] = acc[m][n][r];
      }
    }
}

// conv+silu recompute for 4 consecutive channels d0..d0+3 at token row R (from part2 x-half)
__device__ __forceinline__ float4 conv_silu4(const float* __restrict__ p0,
    const float* __restrict__ p1, const float* __restrict__ cw,
    const float* __restrict__ cb, int R, int d0) {
  int bq = R / 9, pq = R - bq * 9;
  size_t rb = (size_t)R * (2 * NIN) + d0;
  float4 a0 = *reinterpret_cast<const float4*>(p0 + rb);
  float4 a1 = *reinterpret_cast<const float4*>(p1 + rb);
  float cx[4] = {a0.x + a1.x, a0.y + a1.y, a0.z + a1.z, a0.w + a1.w};
  float cm[4] = {0.f, 0.f, 0.f, 0.f}, cp[4] = {0.f, 0.f, 0.f, 0.f};
  if (pq > 0) {
    float4 m0 = *reinterpret_cast<const float4*>(p0 + rb - 2 * NIN);
    float4 m1 = *reinterpret_cast<const float4*>(p1 + rb - 2 * NIN);
    cm[0] = m0.x + m1.x; cm[1] = m0.y + m1.y; cm[2] = m0.z + m1.z; cm[3] = m0.w + m1.w;
  }
  if (pq < Ln - 1) {
    float4 q0 = *reinterpret_cast<const float4*>(p0 + rb + 2 * NIN);
    float4 q1 = *reinterpret_cast<const float4*>(p1 + rb + 2 * NIN);
    cp[0] = q0.x + q1.x; cp[1] = q0.y + q1.y; cp[2] = q0.z + q1.z; cp[3] = q0.w + q1.w;
  }
  float4 w0 = *reinterpret_cast<const float4*>(cw + 3 * d0);
  float4 w1 = *reinterpret_cast<const float4*>(cw + 3 * d0 + 4);
  float4 w2 = *reinterpret_cast<const float4*>(cw + 3 * d0 + 8);
  float wf[12] = {w0.x, w0.y, w0.z, w0.w, w1.x, w1.y, w1.z, w1.w, w2.x, w2.y, w2.z, w2.w};
  float4 cb4 = *reinterpret_cast<const float4*>(cb + d0);
  float cbf[4] = {cb4.x, cb4.y, cb4.z, cb4.w};
  float r[4];
  #pragma unroll
  for (int i = 0; i < 4; ++i) {
    float a = cbf[i] + cm[i] * wf[3 * i] + cx[i] * wf[3 * i + 1] + cp[i] * wf[3 * i + 2];
    r[i] = a / (1.0f + __expf(-a));
  }
  return make_float4(r[0], r[1], r[2], r[3]);
}

// ---------------- xproj split-K partials (fp32), conv+silu fused into A staging ----------
__global__ __launch_bounds__(256) void xproj_kernel(const float* __restrict__ part2,
    const float* __restrict__ cw, const float* __restrict__ cb,
    const float* __restrict__ w, float* __restrict__ part) {
  __shared__ float at[64][44];
  __shared__ float wt[32][80];
  int kc = blockIdx.x, mt = blockIdx.y;
  int t = threadIdx.x;
  int tx = t & 15, ty = t >> 4;
  float acc[4][5] = {};
  int sr = t >> 3, sc4 = (t & 7) * 4;
  const float* p0 = part2;
  const float* p1 = part2 + (size_t)Mn * 2 * NIN;
  for (int k0 = kc * 96; k0 < kc * 96 + 96; k0 += 32) {
    float4 v0 = conv_silu4(p0, p1, cw, cb, mt * 64 + sr,      k0 + sc4);
    float4 v1 = conv_silu4(p0, p1, cw, cb, mt * 64 + sr + 32, k0 + sc4);
    __syncthreads();
    *reinterpret_cast<float4*>(&at[sr][sc4])      = v0;
    *reinterpret_cast<float4*>(&at[sr + 32][sc4]) = v1;
    for (int i = t; i < 32 * 80; i += 256)
      wt[i / 80][i % 80] = w[(size_t)(k0 + i / 80) * 80 + i % 80];
    __syncthreads();
    #pragma unroll
    for (int kk = 0; kk < 32; ++kk) {
      float a0[4], b0[5];
      #pragma unroll
      for (int i = 0; i < 4; ++i) a0[i] = at[ty * 4 + i][kk];
      #pragma unroll
      for (int j = 0; j < 5; ++j) b0[j] = wt[kk][tx + 16 * j];
      #pragma unroll
      for (int i = 0; i < 4; ++i)
        #pragma unroll
        for (int j = 0; j < 5; ++j)
          acc[i][j] = fmaf(a0[i], b0[j], acc[i][j]);
    }
  }
  #pragma unroll
  for (int i = 0; i < 4; ++i)
    #pragma unroll
    for (int j = 0; j < 5; ++j)
      part[((size_t)kc * Mn + mt * 64 + ty * 4 + i) * 80 + tx + 16 * j] = acc[i][j];
}

// ---------------- fused: split-K reduce + pe_b bias + LayerNorm -> interleaved h2 --------
__global__ __launch_bounds__(256) void ln_kernel(const float* __restrict__ part1,
    const float* __restrict__ peb, const float* __restrict__ g, const float* __restrict__ be,
    unsigned short* __restrict__ h2) {
  int row = blockIdx.x;
  int t = threadIdx.x;
  float vq[3];
  #pragma unroll
  for (int q = 0; q < 3; ++q) {
    int c = t + q * 256;
    float v = peb[c];
    #pragma unroll
    for (int ks = 0; ks < 8; ++ks)
      v += part1[((size_t)ks * Mn + row) * HID + c];
    vq[q] = v;
  }
  float s  = vq[0] + vq[1] + vq[2];
  float s2 = vq[0] * vq[0] + vq[1] * vq[1] + vq[2] * vq[2];
  #pragma unroll
  for (int o = 32; o > 0; o >>= 1) {
    s  += __shfl_down(s,  o, 64);
    s2 += __shfl_down(s2, o, 64);
  }
  __shared__ float red[8];
  int wid = t >> 6, lane = t & 63;
  if (lane == 0) { red[wid] = s; red[4 + wid] = s2; }
  __syncthreads();
  float S  = red[0] + red[1] + red[2] + red[3];
  float S2 = red[4] + red[5] + red[6] + red[7];
  float mu  = S * (1.0f / HID);
  float var = S2 * (1.0f / HID) - mu * mu;
  float inv = rsqrtf(var + 1e-5f);
  #pragma unroll
  for (int q = 0; q < 3; ++q) {
    int c = t + q * 256;
    float hv = (vq[q] - mu) * inv * g[c] + be[c];
    unsigned short hi, lo;
    split_bf(hv, hi, lo);
    size_t base = (size_t)row * (2 * HID) + col2(c);
    h2[base] = hi; h2[base + 32] = lo;
  }
}

// -- fused scan: xproj reduce + dt-proj + softplus + conv-recompute + scan + D + z-gate --
__global__ __launch_bounds__(256) void scan_kernel(const float* __restrict__ partx,
    const float* __restrict__ A_log, const float* __restrict__ Dp,
    const float* __restrict__ part2, const float* __restrict__ dtw,
    const float* __restrict__ dtb, const float* __restrict__ cw,
    const float* __restrict__ cb, unsigned short* __restrict__ ya2) {
  __shared__ float wdt[DTR * 256];                    // 48 KB
  __shared__ float dbc9[Ln][DTR];
  __shared__ float Bsh[Ln][NST], Csh[Ln][NST];
  int b      = blockIdx.x / (NIN / 256);
  int dchunk = blockIdx.x % (NIN / 256);
  int t = threadIdx.x;
  float4* w4 = reinterpret_cast<float4*>(wdt);
  #pragma unroll
  for (int it = 0; it < 12; ++it) {
    int i4 = it * 256 + t;
    int k = i4 >> 6, c4 = i4 & 63;
    w4[i4] = *reinterpret_cast<const float4*>(dtw + (size_t)k * NIN + dchunk * 256 + c4 * 4);
  }
  for (int i = t; i < Ln * 80; i += 256) {
    int p = i / 80, k = i - p * 80;
    size_t off = (size_t)(b * Ln + p) * 80 + k;
    float s = 0.f;
    #pragma unroll
    for (int ks = 0; ks < XKS; ++ks) s += partx[(size_t)ks * (Mn * 80) + off];
    if (k < DTR)            dbc9[p][k] = s;
    else if (k < DTR + NST) Bsh[p][k - DTR] = s;
    else                    Csh[p][k - DTR - NST] = s;
  }
  __syncthreads();
  int d = dchunk * 256 + t;
  float Ar[NST];
  #pragma unroll
  for (int n = 0; n < NST; ++n) Ar[n] = -__expf(A_log[(size_t)d * NST + n]);
  float s[NST];
  #pragma unroll
  for (int n = 0; n < NST; ++n) s[n] = 0.0f;
  float Dv = Dp[d];
  float bt = dtb[d];
  float w0 = cw[3 * d], w1 = cw[3 * d + 1], w2 = cw[3 * d + 2];
  float cbv = cb[d];
  int cc = col2(d);
  const float* px0 = part2 + d;                       // x-half
  const float* px1 = px0 + (size_t)Mn * 2 * NIN;
  const float* z0  = part2 + NIN + d;                 // z-half
  const float* z1  = z0 + (size_t)Mn * 2 * NIN;
  size_t row0 = (size_t)(b * Ln) * (2 * NIN);
  // rolling conv window over p
  float xm = 0.f;
  float x0 = px0[row0] + px1[row0];
  for (int p = 0; p < Ln; ++p) {
    size_t roff = row0 + (size_t)p * (2 * NIN);
    float xp = 0.f;
    if (p < Ln - 1) xp = px0[roff + 2 * NIN] + px1[roff + 2 * NIN];
    float a0 = cbv + xm * w0 + x0 * w1 + xp * w2;
    float u = a0 / (1.0f + __expf(-a0));              // silu(conv)
    // delta = softplus(dbc[:, :48] @ dtproj_w + bias)
    float a = bt;
    #pragma unroll
    for (int k = 0; k < DTR; ++k) a = fmaf(dbc9[p][k], wdt[k * 256 + t], a);
    float dl = fmaxf(a, 0.0f) + log1pf(__expf(-fabsf(a)));
    float du = dl * u;
    float y = 0.0f;
    #pragma unroll
    for (int n = 0; n < NST; ++n) {
      float dA = __expf(dl * Ar[n]);
      s[n] = dA * s[n] + du * Bsh[p][n];
      y += s[n] * Csh[p][n];
    }
    float zv = z0[roff] + z1[roff];
    float sz = zv / (1.0f + __expf(-zv));
    float yv = (y + u * Dv) * sz;
    unsigned short hi, lo;
    split_bf(yv, hi, lo);
    ya2[roff + cc] = hi; ya2[roff + cc + 32] = lo;
    xm = x0; x0 = xp;
  }
}

// -------- fused: split-K reduce + transpose + bilinear resize, coalesced writes --------
__global__ __launch_bounds__(256) void resize_kernel(const float* __restrict__ part3,
                                                     float* __restrict__ out) {
  __shared__ float v[32][10];
  int blk = blockIdx.x;                               // Bn * (Cn/32) = 8192
  int b = blk >> 6, cg = blk & 63;
  int t = threadIdx.x;
  size_t MN3 = (size_t)Mn * Cn;
  for (int i = t; i < 288; i += 256) {
    int p = i >> 5, c = i & 31;
    size_t base = (size_t)(b * Ln + p) * Cn + cg * 32 + c;
    v[c][p] = part3[base] + part3[base + MN3];
  }
  __syncthreads();
  int ch = t >> 3, sub = t & 7;
  float* dst = out + ((size_t)b * Cn + cg * 32 + ch) * 288;
  #pragma unroll
  for (int q = 0; q < 9; ++q) {
    int f = sub + q * 8;
    int y = f / 3, xq = f - y * 3;
    float fy  = (y + 0.5f) * 0.125f - 0.5f;
    float fyf = floorf(fy);
    float wy  = fy - fyf;
    int yy = (int)fyf;
    int y0 = min(2, max(0, yy)), y1 = min(2, max(0, yy + 1));
    float rr[3];
    #pragma unroll
    for (int j = 0; j < 3; ++j)
      rr[j] = v[ch][y0 * 3 + j] * (1.0f - wy) + v[ch][y1 * 3 + j] * wy;
    float ov[4];
    #pragma unroll
    for (int xi = 0; xi < 4; ++xi) {
      int xo = xq * 4 + xi;
      float fx  = (xo + 0.5f) * 0.25f - 0.5f;
      float fxf = floorf(fx);
      float wx  = fx - fxf;
      int xx = (int)fxf;
      int x0 = min(2, max(0, xx)), x1 = min(2, max(0, xx + 1));
      ov[xi] = rr[x0] * (1.0f - wx) + rr[x1] * wx;
    }
    *reinterpret_cast<float4*>(dst + f * 4) = make_float4(ov[0], ov[1], ov[2], ov[3]);
  }
}

extern "C" void kernel_launch(void* const* d_in, const int* in_sizes, int n_in,
                              void* d_out, int out_size, void* d_ws, size_t ws_size,
                              hipStream_t stream) {
  const float* x        = (const float*)d_in[0];
  const float* pe_w     = (const float*)d_in[1];
  const float* pe_b     = (const float*)d_in[2];
  const float* ln_g     = (const float*)d_in[3];
  const float* ln_b     = (const float*)d_in[4];
  const float* in_w     = (const float*)d_in[5];
  const float* conv_w   = (const float*)d_in[6];
  const float* conv_b   = (const float*)d_in[7];
  const float* A_log    = (const float*)d_in[8];
  const float* xproj_w  = (const float*)d_in[9];
  const float* dtproj_w = (const float*)d_in[10];
  const float* dtproj_b = (const float*)d_in[11];
  const float* D_param  = (const float*)d_in[12];
  const float* out_w    = (const float*)d_in[13];
  float* out = (float*)d_out;
  char* ws = (char*)d_ws;

  size_t o = 0;
  auto alloc = [&](size_t bytes) { size_t r = o; o += (bytes + 255) & ~(size_t)255; return r; };
  unsigned short* tok2  = (unsigned short*)(ws + alloc((size_t)Mn * 2 * Cn * 2));
  unsigned short* peT2  = (unsigned short*)(ws + alloc((size_t)HID * 2 * Cn * 2));
  unsigned short* inT2  = (unsigned short*)(ws + alloc((size_t)2 * NIN * 2 * HID * 2));
  unsigned short* outT2 = (unsigned short*)(ws + alloc((size_t)Cn * 2 * NIN * 2));
  unsigned short* h2    = (unsigned short*)(ws + alloc((size_t)Mn * 2 * HID * 2));
  unsigned short* ya2   = (unsigned short*)(ws + alloc((size_t)Mn * 2 * NIN * 2));
  float* part1 = (float*)(ws + alloc((size_t)8 * Mn * HID * 4));
  float* part2 = (float*)(ws + alloc((size_t)2 * Mn * 2 * NIN * 4));
  float* part3 = (float*)(ws + alloc((size_t)2 * Mn * Cn * 4));
  float* partx = (float*)(ws + alloc((size_t)XKS * Mn * 80 * 4));

  // prep: weight transposes (6912 blocks) + pooling (8192 blocks)
  prep_kernel<<<15104, 256, 0, stream>>>(pe_w, in_w, out_w, x, peT2, inT2, outT2, tok2);

  // tok @ pe_w : M=1152 N=768 K=2048, split-K=8 -> grid 432
  mgemm_kernel<<<dim3(HID / 128, Mn / 128, 8), 256, 0, stream>>>(
      tok2, peT2, part1, Mn, HID, Cn, Cn / 8);
  ln_kernel<<<Mn, 256, 0, stream>>>(part1, pe_b, ln_g, ln_b, h2);
  // h @ in_w : M=1152 N=3072 K=768, split-K=2 -> grid 432
  mgemm_kernel<<<dim3(2 * NIN / 128, Mn / 128, 2), 256, 0, stream>>>(
      h2, inT2, part2, Mn, 2 * NIN, HID, HID / 2);
  xproj_kernel<<<dim3(XKS, Mn / 64), 256, 0, stream>>>(part2, conv_w, conv_b, xproj_w, partx);
  scan_kernel<<<Bn * (NIN / 256), 256, 0, stream>>>(
      partx, A_log, D_param, part2, dtproj_w, dtproj_b, conv_w, conv_b, ya2);
  // ya @ out_w : M=1152 N=2048 K=1536, split-K=2 -> grid 288
  mgemm_kernel<<<dim3(Cn / 128, Mn / 128, 2), 256, 0, stream>>>(
      ya2, outT2, part3, Mn, Cn, NIN, NIN / 2);
  resize_kernel<<<Bn * (Cn / 32), 256, 0, stream>>>(part3, out);
}